// Round 8
// baseline (585.558 us; speedup 1.0000x reference)
//
#include <hip/hip_runtime.h>
#include <math.h>

#define NH 12
#define HD 32
#define GN 48
#define TK 96
#define NB 2
#define NN 1600
#define CC 384
#define BHN (NB*NH)          // 24
#define QKV_COLS (3*NH*HD)   // 1152
#define NQ (BHN*NN)          // 38400 total (b,h,n) queries

// ---------------------------------------------------------------------------
// GEMM: out = A[M,K] @ B[N,K]^T   (both row-major; B rows are output cols)
// MODE 0: scatter epilogue into q/k/v [B,h,N,d]   MODE 1: plain store [M,N]
// ---------------------------------------------------------------------------
template<int MODE>
__global__ __launch_bounds__(256)
void gemm_tile(const float* __restrict__ A, const float* __restrict__ B,
               float* __restrict__ o0, float* __restrict__ o1, float* __restrict__ o2,
               int M, int N, int K)
{
    __shared__ float As[16][64];
    __shared__ float Bs[16][64];
    const int tid = threadIdx.x;
    const int tx = tid & 15, ty = tid >> 4;
    const int m0 = blockIdx.y * 64, n0 = blockIdx.x * 64;
    const int lr = tid >> 2;          // tile row 0..63
    const int lc = (tid & 3) * 4;     // k-seg 0,4,8,12
    float acc[4][4] = {};

    for (int k0 = 0; k0 < K; k0 += 16) {
        float4 av = *(const float4*)&A[(m0 + lr) * K + k0 + lc];
        float4 bv = *(const float4*)&B[(n0 + lr) * K + k0 + lc];
        __syncthreads();   // previous iter's compute done before overwrite
        As[lc+0][lr] = av.x; As[lc+1][lr] = av.y; As[lc+2][lr] = av.z; As[lc+3][lr] = av.w;
        Bs[lc+0][lr] = bv.x; Bs[lc+1][lr] = bv.y; Bs[lc+2][lr] = bv.z; Bs[lc+3][lr] = bv.w;
        __syncthreads();
        #pragma unroll
        for (int kk = 0; kk < 16; ++kk) {
            float4 a4 = *(const float4*)&As[kk][ty*4];
            float4 b4 = *(const float4*)&Bs[kk][tx*4];
            float a[4] = {a4.x, a4.y, a4.z, a4.w};
            float b[4] = {b4.x, b4.y, b4.z, b4.w};
            #pragma unroll
            for (int i = 0; i < 4; ++i)
                #pragma unroll
                for (int j = 0; j < 4; ++j)
                    acc[i][j] = fmaf(a[i], b[j], acc[i][j]);
        }
    }

    if (MODE == 0) {
        #pragma unroll
        for (int i = 0; i < 4; ++i) {
            int row = m0 + ty*4 + i;
            int b  = row / NN;
            int nn = row - b * NN;
            #pragma unroll
            for (int j = 0; j < 4; ++j) {
                int col = n0 + tx*4 + j;
                int which = col / CC;          // uniform per tile (384 % 64 == 0)
                int rem = col - which * CC;
                int hh = rem >> 5, dd = rem & 31;
                float* dst = (which == 0) ? o0 : (which == 1) ? o1 : o2;
                dst[((b*NH + hh)*NN + nn)*HD + dd] = acc[i][j];
            }
        }
    } else {
        #pragma unroll
        for (int i = 0; i < 4; ++i) {
            int row = m0 + ty*4 + i;
            float4 st = make_float4(acc[i][0], acc[i][1], acc[i][2], acc[i][3]);
            *(float4*)&o0[row * N + n0 + tx*4] = st;
        }
    }
}

// ---------------------------------------------------------------------------
// Kernel 2: per-query group argmax (gidx), strict > == jnp.argmax tie-break
// ---------------------------------------------------------------------------
__global__ __launch_bounds__(256)
void group_route(const float* __restrict__ q, const float* __restrict__ wgp,
                 int* __restrict__ gidx)
{
    int t = blockIdx.x * 256 + threadIdx.x;   // [0, NQ)
    int bh = t / NN;
    int hh = bh % NH;
    const float* qp = q + t * HD;
    float qr[HD];
    #pragma unroll
    for (int i = 0; i < HD; i += 4) {
        float4 x = *(const float4*)&qp[i];
        qr[i] = x.x; qr[i+1] = x.y; qr[i+2] = x.z; qr[i+3] = x.w;
    }
    float best = -INFINITY; int bg = 0;
    for (int g = 0; g < GN; ++g) {
        const float* gp = wgp + hh*GN*HD + g*HD;
        float s = 0.f;
        #pragma unroll
        for (int i = 0; i < HD; i += 4) {
            float4 w = *(const float4*)&gp[i];
            s += qr[i]*w.x + qr[i+1]*w.y + qr[i+2]*w.z + qr[i+3]*w.w;
        }
        if (s > best) { best = s; bg = g; }
    }
    gidx[t] = bg;
}

// ---------------------------------------------------------------------------
// Kernel 3a (v3): per-(bh,g) deterministic group-mean (register accumulation,
// round-1 summation order) + query bucketing (qperm/qoff/qcnt) for attention.
// 1152 blocks.
// ---------------------------------------------------------------------------
__global__ __launch_bounds__(256)
void qmean_all2(const float* __restrict__ q, const int* __restrict__ gidx,
                float* __restrict__ qmean, int* __restrict__ qperm,
                int* __restrict__ qoff, int* __restrict__ qcnt)
{
    __shared__ float part[8][HD];
    __shared__ int   cnts[8];
    __shared__ int   off_s, pos_s;
    const int bid = blockIdx.x;       // bh*GN + g
    const int g = bid % GN, bh = bid / GN;
    const int tid = threadIdx.x;
    const int s = tid >> 5, dd = tid & 31;

    const int* __restrict__ gx = gidx + bh*NN;
    const float* __restrict__ qb = q + bh*NN*HD;

    if (tid == 0) { off_s = 0; pos_s = 0; }

    float p = 0.f; int c = 0;
    for (int n = s; n < NN; n += 8) {
        if (gx[n] == g) { p += qb[n*HD + dd]; c++; }
    }
    part[s][dd] = p;
    if (dd == 0) cnts[s] = c;
    __syncthreads();                  // part[] + off_s/pos_s init visible

    if (tid < HD) {
        float sum = 0.f; int ct = 0;
        #pragma unroll
        for (int ss = 0; ss < 8; ++ss) { sum += part[ss][tid]; ct += cnts[ss]; }
        qmean[bid*HD + tid] = ct ? sum / (float)ct : 0.f;
    }

    // bucketing: offset = #queries in groups < g (gx row is L1-hot now)
    int mo = 0;
    for (int n = tid; n < NN; n += 256) mo += (gx[n] < g);
    atomicAdd(&off_s, mo);
    __syncthreads();
    for (int n = tid; n < NN; n += 256) {
        if (gx[n] == g) {
            int pp = atomicAdd(&pos_s, 1);
            qperm[bh*NN + off_s + pp] = n;
        }
    }
    __syncthreads();
    if (tid == 0) { qoff[bid] = off_s; qcnt[bid] = pos_s; }
}

// ---------------------------------------------------------------------------
// Kernel 3b: scores[bh*GN+g][n] = qmean[bh,g] . k[bh,n]. Thread owns one n,
// k-row in registers, qmean tile in LDS (broadcast reads), coalesced stores.
// ---------------------------------------------------------------------------
__global__ __launch_bounds__(256)
void score_all(const float* __restrict__ qmean, const float* __restrict__ k,
               float* __restrict__ scores)
{
    __shared__ float Qs[GN][HD];          // 6 KB
    const int bh = blockIdx.y;
    const int tid = threadIdx.x;
    const int n = blockIdx.x*256 + tid;
    for (int i = tid; i < GN*HD; i += 256)
        ((float*)Qs)[i] = qmean[bh*GN*HD + i];
    __syncthreads();
    if (n >= NN) return;
    const float* __restrict__ kp = k + (bh*NN + n)*HD;
    float4 kr[8];
    #pragma unroll
    for (int c = 0; c < 8; ++c) kr[c] = *(const float4*)&kp[c*4];
    for (int g = 0; g < GN; ++g) {
        float s = 0.f;
        #pragma unroll
        for (int c = 0; c < 8; ++c) {
            float4 qv = *(const float4*)&Qs[g][c*4];   // same-addr broadcast
            s += kr[c].x*qv.x + kr[c].y*qv.y + kr[c].z*qv.z + kr[c].w*qv.w;
        }
        scores[(bh*GN + g)*NN + n] = s;               // coalesced per g
    }
}

// ---------------------------------------------------------------------------
// Kernel 3c: per-WAVE barrier-free radix top-96. Each 64-lane wave owns one
// (bh,g) row of 1600 scores: keys + 256-bin hist live in per-wave LDS slices
// (DS ops from a wave complete in program order -> no __syncthreads).
// Suffix-scan in registers via shfl; pivot via ballot; collect via ballot-
// compaction in ascending index order (== lax.top_k lowest-index ties).
// ---------------------------------------------------------------------------
__global__ __launch_bounds__(256)
void topk_radix(const float* __restrict__ scores, int* __restrict__ topk)
{
    __shared__ unsigned keysL[4][NN];     // 25.6 KB
    __shared__ unsigned histL[4][256];    // 4 KB
    const int tid = threadIdx.x;
    const int w = tid >> 6, lane = tid & 63;
    const int gid = blockIdx.x*4 + w;     // (bh*GN + g) in [0,1152)
    const float* __restrict__ row = scores + gid*NN;
    unsigned* keys = keysL[w];
    unsigned* hist = histL[w];

    // load + order-preserving transform (1600 = 25*64 exactly)
    #pragma unroll
    for (int i = 0; i < 25; ++i) {
        int m = lane + 64*i;
        unsigned u = __float_as_uint(row[m]);
        u = (u & 0x80000000u) ? ~u : (u | 0x80000000u);
        keys[m] = u;
    }

    unsigned prefix = 0, r = TK;
    #pragma unroll
    for (int pass = 0; pass < 4; ++pass) {
        const int shift = 24 - 8*pass;
        #pragma unroll
        for (int j = 0; j < 4; ++j) hist[lane*4 + j] = 0;
        #pragma unroll
        for (int i = 0; i < 25; ++i) {
            unsigned u = keys[lane + 64*i];
            bool match = (pass == 0) || ((u >> (shift+8)) == (prefix >> (shift+8)));
            if (match) atomicAdd(&hist[(u >> shift) & 255u], 1u);
        }
        // suffix scan: lane holds bins 4L..4L+3
        uint4 h = *(const uint4*)&hist[lane*4];
        unsigned s3 = h.w, s2 = h.z + s3, s1 = h.y + s2, s0 = h.x + s1;
        unsigned I = s0;                      // inclusive suffix over lane totals
        #pragma unroll
        for (int off = 1; off < 64; off <<= 1) {
            unsigned t = __shfl_down(I, off);
            if (lane + off < 64) I += t;
        }
        unsigned E = I - s0;                  // strict suffix (lanes > L)
        unsigned sf[5] = {E+s0, E+s1, E+s2, E+s3, E};
        int bj = -1; unsigned subc = 0;
        #pragma unroll
        for (int j = 0; j < 4; ++j)
            if (sf[j] >= r && sf[j+1] < r) { bj = j; subc = sf[j+1]; }
        unsigned long long mask = __ballot(bj >= 0);   // exactly one bit set
        int src = __ffsll(mask) - 1;
        int bstar = __shfl(lane*4 + bj, src);
        unsigned sub = (unsigned)__shfl((int)subc, src);
        prefix |= ((unsigned)bstar) << shift;
        r -= sub;
    }
    const unsigned P = prefix;   // exact 96th-largest key; r = #equals to take

    // collect: all keys > P, then first r keys == P (ascending index)
    int* tko = topk + gid*TK;
    int base = 0;
    #pragma unroll
    for (int i = 0; i < 25; ++i) {
        int m = lane + 64*i;
        bool gt = (keys[m] > P);
        unsigned long long mask = __ballot(gt);
        if (gt) tko[base + __popcll(mask & ((1ull << lane) - 1ull))] = m;
        base += (int)__popcll(mask);
    }
    #pragma unroll
    for (int i = 0; i < 25; ++i) {
        int m = lane + 64*i;
        bool eq = (keys[m] == P);
        unsigned long long mask = __ballot(eq);
        if (eq) {
            int pos = base + (int)__popcll(mask & ((1ull << lane) - 1ull));
            if (pos < TK) tko[pos] = m;
        }
        base += (int)__popcll(mask);
    }
}

// ---------------------------------------------------------------------------
// Kernel 4 (v5): group-bucketed attention with v4's low-register inner loop.
// One block per (bh,g): K/V top-96 rows staged in LDS once (24 KB), then the
// group's queries 32/pass, 8 lanes each. LDS reads Ks[j][dl*4..]: address
// depends only on dl -> 8 distinct 16B segments covering all 32 banks,
// broadcast across query-groups -> conflict-free. No index shuffles (keys
// dense 0..95 in LDS). Per-thread state: q4 + sc[12] + acc4 (~35 VGPR).
// ---------------------------------------------------------------------------
__global__ __launch_bounds__(256, 4)
void sparse_attn5(const float* __restrict__ q, const float* __restrict__ k,
                  const float* __restrict__ v, const int* __restrict__ topk,
                  const int* __restrict__ qperm, const int* __restrict__ qoff,
                  const int* __restrict__ qcnt, float* __restrict__ out)
{
    __shared__ float Ks[TK*HD];   // 12 KB
    __shared__ float Vs[TK*HD];   // 12 KB

    const int bid = blockIdx.x;   // bh*GN + g
    const int bh = bid / GN;
    const int nq = qcnt[bid];
    if (nq == 0) return;          // uniform per block
    const int off = qoff[bid];
    const int tid = threadIdx.x;

    const int* __restrict__ tk = topk + bid*TK;
    const float* __restrict__ kb = k + bh*NN*HD;
    const float* __restrict__ vb = v + bh*NN*HD;

    // stage K,V: 768 float4 each; 8 consecutive lanes fetch one 128B row
    for (int idx = tid; idx < TK*8; idx += 256) {
        int row = idx >> 3, ch = idx & 7;
        int r = tk[row];
        ((float4*)Ks)[idx] = *(const float4*)&kb[r*HD + ch*4];
        ((float4*)Vs)[idx] = *(const float4*)&vb[r*HD + ch*4];
    }
    __syncthreads();

    const float scale = 0.17677669529663687f;   // 32^-0.5
    const int qs = tid >> 3;            // query slot 0..31
    const int dl = tid & 7;             // lane in 8-lane group
    const int lb = (tid & 63) & ~7;     // wave-lane base of the group
    const int b = bh / NH, hh = bh - b*NH;
    const float* __restrict__ qbase = q + bh*NN*HD;
    const int* __restrict__ qlist = qperm + bh*NN + off;

    for (int it0 = 0; it0 < nq; it0 += 32) {
        const int qi = it0 + qs;
        const bool act = (qi < nq);
        const int nn = qlist[act ? qi : nq-1];   // whole 8-lane group inactive together

        float4 q4 = *(const float4*)&qbase[nn*HD + dl*4];

        // phase 1: lane dl owns keys t*8+dl; per key all 8 lanes cooperate
        float sc[12];
        #pragma unroll
        for (int t = 0; t < 12; ++t) {
            float keep = 0.f;
            #pragma unroll
            for (int u = 0; u < 8; ++u) {
                float4 w = *(const float4*)&Ks[(t*8 + u)*HD + dl*4];
                float p = fmaf(q4.x, w.x, fmaf(q4.y, w.y, fmaf(q4.z, w.z, q4.w*w.w)));
                p += __shfl_xor(p, 1);
                p += __shfl_xor(p, 2);
                p += __shfl_xor(p, 4);
                if (u == dl) keep = p;
            }
            sc[t] = keep * scale;
        }

        // softmax across the 96 scores (8-lane shfl reduce)
        float m = -INFINITY;
        #pragma unroll
        for (int t = 0; t < 12; ++t) m = fmaxf(m, sc[t]);
        #pragma unroll
        for (int o = 1; o < 8; o <<= 1) m = fmaxf(m, __shfl_xor(m, o));
        float l = 0.f;
        #pragma unroll
        for (int t = 0; t < 12; ++t) { sc[t] = __expf(sc[t] - m); l += sc[t]; }
        #pragma unroll
        for (int o = 1; o < 8; o <<= 1) l += __shfl_xor(l, o);
        const float inv = 1.0f / l;
        #pragma unroll
        for (int t = 0; t < 12; ++t) sc[t] *= inv;

        // phase 2: weighted V sum; lane owns dims 4dl..4dl+3 (LDS broadcast)
        float a0 = 0.f, a1 = 0.f, a2 = 0.f, a3 = 0.f;
        #pragma unroll
        for (int t = 0; t < 12; ++t) {
            #pragma unroll
            for (int u = 0; u < 8; ++u) {
                const float p = __shfl(sc[t], lb + u);
                float4 vv = *(const float4*)&Vs[(t*8 + u)*HD + dl*4];
                a0 = fmaf(p, vv.x, a0);
                a1 = fmaf(p, vv.y, a1);
                a2 = fmaf(p, vv.z, a2);
                a3 = fmaf(p, vv.w, a3);
            }
        }

        if (act) {
            float* op = out + (b*NN + nn)*CC + hh*HD + dl*4;
            *(float4*)op = make_float4(a0, a1, a2, a3);
        }
    }
}

// ---------------------------------------------------------------------------
extern "C" void kernel_launch(void* const* d_in, const int* in_sizes, int n_in,
                              void* d_out, int out_size, void* d_ws, size_t ws_size,
                              hipStream_t stream)
{
    const float* x      = (const float*)d_in[0];   // [B,H,W,C] = [3200, 384]
    const float* w_qkv  = (const float*)d_in[1];   // [1152, 384]
    const float* w_gp   = (const float*)d_in[2];   // [48, 384] -> (12,48,32)
    const float* w_proj = (const float*)d_in[3];   // [384, 384]
    float* out = (float*)d_out;                    // [B,H,W,C]

    float* ws = (float*)d_ws;
    float* q        = ws;                 // [B,h,N,d] 1228800
    float* kk       = ws + 1228800;
    float* vv       = ws + 2457600;
    float* attn_out = ws + 3686400;       // [B,N,h*d] 1228800
    float* scores   = ws + 4915200;       // [1152][1600] 1843200
    float* qmean    = ws + 6758400;       // [1152][32]   36864
    int*   iws      = (int*)(ws + 6795264);
    int*   gidx     = iws;                // 38400
    int*   topk     = iws + 38400;        // 110592
    int*   qperm    = iws + 38400 + 110592;            // 38400
    int*   qoff     = iws + 38400 + 110592 + 38400;    // 1152
    int*   qcnt     = qoff + 1152;                     // 1152

    // 1) QKV projection, scatter into q/k/v
    gemm_tile<0><<<dim3(QKV_COLS/64, (NB*NN)/64), 256, 0, stream>>>(
        x, w_qkv, q, kk, vv, NB*NN, QKV_COLS, CC);

    // 2) query -> group routing
    group_route<<<NQ/256, 256, 0, stream>>>(q, w_gp, gidx);

    // 3a) deterministic group means + query buckets (1152 blocks)
    qmean_all2<<<BHN*GN, 256, 0, stream>>>(q, gidx, qmean, qperm, qoff, qcnt);

    // 3b) group->key score matrix
    score_all<<<dim3(7, BHN), 256, 0, stream>>>(qmean, kk, scores);

    // 3c) per-wave barrier-free radix top-96
    topk_radix<<<(BHN*GN)/4, 256, 0, stream>>>(scores, topk);

    // 4) group-bucketed sparse attention (K/V in LDS, low-VGPR inner loop)
    sparse_attn5<<<BHN*GN, 256, 0, stream>>>(q, kk, vv, topk, qperm, qoff, qcnt, attn_out);

    // 5) output projection
    gemm_tile<1><<<dim3(CC/64, (NB*NN)/64), 256, 0, stream>>>(
        attn_out, w_proj, out, nullptr, nullptr, NB*NN, CC, CC);
}

// Round 9
// 399.597 us; speedup vs baseline: 1.4654x; 1.4654x over previous
//
#include <hip/hip_runtime.h>
#include <math.h>

#define NH 12
#define HD 32
#define GN 48
#define TK 96
#define NB 2
#define NN 1600
#define CC 384
#define BHN (NB*NH)          // 24
#define QKV_COLS (3*NH*HD)   // 1152
#define NQ (BHN*NN)          // 38400 total (b,h,n) queries

// ---------------------------------------------------------------------------
// GEMM: out = A[M,K] @ B[N,K]^T   (both row-major; B rows are output cols)
// MODE 0: scatter epilogue into q/k/v [B,h,N,d]   MODE 1: plain store [M,N]
// ---------------------------------------------------------------------------
template<int MODE>
__global__ __launch_bounds__(256)
void gemm_tile(const float* __restrict__ A, const float* __restrict__ B,
               float* __restrict__ o0, float* __restrict__ o1, float* __restrict__ o2,
               int M, int N, int K)
{
    __shared__ float As[16][64];
    __shared__ float Bs[16][64];
    const int tid = threadIdx.x;
    const int tx = tid & 15, ty = tid >> 4;
    const int m0 = blockIdx.y * 64, n0 = blockIdx.x * 64;
    const int lr = tid >> 2;          // tile row 0..63
    const int lc = (tid & 3) * 4;     // k-seg 0,4,8,12
    float acc[4][4] = {};

    for (int k0 = 0; k0 < K; k0 += 16) {
        float4 av = *(const float4*)&A[(m0 + lr) * K + k0 + lc];
        float4 bv = *(const float4*)&B[(n0 + lr) * K + k0 + lc];
        __syncthreads();   // previous iter's compute done before overwrite
        As[lc+0][lr] = av.x; As[lc+1][lr] = av.y; As[lc+2][lr] = av.z; As[lc+3][lr] = av.w;
        Bs[lc+0][lr] = bv.x; Bs[lc+1][lr] = bv.y; Bs[lc+2][lr] = bv.z; Bs[lc+3][lr] = bv.w;
        __syncthreads();
        #pragma unroll
        for (int kk = 0; kk < 16; ++kk) {
            float4 a4 = *(const float4*)&As[kk][ty*4];
            float4 b4 = *(const float4*)&Bs[kk][tx*4];
            float a[4] = {a4.x, a4.y, a4.z, a4.w};
            float b[4] = {b4.x, b4.y, b4.z, b4.w};
            #pragma unroll
            for (int i = 0; i < 4; ++i)
                #pragma unroll
                for (int j = 0; j < 4; ++j)
                    acc[i][j] = fmaf(a[i], b[j], acc[i][j]);
        }
    }

    if (MODE == 0) {
        #pragma unroll
        for (int i = 0; i < 4; ++i) {
            int row = m0 + ty*4 + i;
            int b  = row / NN;
            int nn = row - b * NN;
            #pragma unroll
            for (int j = 0; j < 4; ++j) {
                int col = n0 + tx*4 + j;
                int which = col / CC;          // uniform per tile (384 % 64 == 0)
                int rem = col - which * CC;
                int hh = rem >> 5, dd = rem & 31;
                float* dst = (which == 0) ? o0 : (which == 1) ? o1 : o2;
                dst[((b*NH + hh)*NN + nn)*HD + dd] = acc[i][j];
            }
        }
    } else {
        #pragma unroll
        for (int i = 0; i < 4; ++i) {
            int row = m0 + ty*4 + i;
            float4 st = make_float4(acc[i][0], acc[i][1], acc[i][2], acc[i][3]);
            *(float4*)&o0[row * N + n0 + tx*4] = st;
        }
    }
}

// ---------------------------------------------------------------------------
// Kernel 2: per-query group argmax (gidx), strict > == jnp.argmax tie-break
// ---------------------------------------------------------------------------
__global__ __launch_bounds__(256)
void group_route(const float* __restrict__ q, const float* __restrict__ wgp,
                 int* __restrict__ gidx)
{
    int t = blockIdx.x * 256 + threadIdx.x;   // [0, NQ)
    int bh = t / NN;
    int hh = bh % NH;
    const float* qp = q + t * HD;
    float qr[HD];
    #pragma unroll
    for (int i = 0; i < HD; i += 4) {
        float4 x = *(const float4*)&qp[i];
        qr[i] = x.x; qr[i+1] = x.y; qr[i+2] = x.z; qr[i+3] = x.w;
    }
    float best = -INFINITY; int bg = 0;
    for (int g = 0; g < GN; ++g) {
        const float* gp = wgp + hh*GN*HD + g*HD;
        float s = 0.f;
        #pragma unroll
        for (int i = 0; i < HD; i += 4) {
            float4 w = *(const float4*)&gp[i];
            s += qr[i]*w.x + qr[i+1]*w.y + qr[i+2]*w.z + qr[i+3]*w.w;
        }
        if (s > best) { best = s; bg = g; }
    }
    gidx[t] = bg;
}

// ---------------------------------------------------------------------------
// Kernel 3a (v3): per-(bh,g) deterministic group-mean (register accumulation,
// round-1 summation order) + query bucketing (qperm/qoff/qcnt) for attention.
// 1152 blocks.
// ---------------------------------------------------------------------------
__global__ __launch_bounds__(256)
void qmean_all2(const float* __restrict__ q, const int* __restrict__ gidx,
                float* __restrict__ qmean, int* __restrict__ qperm,
                int* __restrict__ qoff, int* __restrict__ qcnt)
{
    __shared__ float part[8][HD];
    __shared__ int   cnts[8];
    __shared__ int   off_s, pos_s;
    const int bid = blockIdx.x;       // bh*GN + g
    const int g = bid % GN, bh = bid / GN;
    const int tid = threadIdx.x;
    const int s = tid >> 5, dd = tid & 31;

    const int* __restrict__ gx = gidx + bh*NN;
    const float* __restrict__ qb = q + bh*NN*HD;

    if (tid == 0) { off_s = 0; pos_s = 0; }

    float p = 0.f; int c = 0;
    for (int n = s; n < NN; n += 8) {
        if (gx[n] == g) { p += qb[n*HD + dd]; c++; }
    }
    part[s][dd] = p;
    if (dd == 0) cnts[s] = c;
    __syncthreads();                  // part[] + off_s/pos_s init visible

    if (tid < HD) {
        float sum = 0.f; int ct = 0;
        #pragma unroll
        for (int ss = 0; ss < 8; ++ss) { sum += part[ss][tid]; ct += cnts[ss]; }
        qmean[bid*HD + tid] = ct ? sum / (float)ct : 0.f;
    }

    // bucketing: offset = #queries in groups < g (gx row is L1-hot now)
    int mo = 0;
    for (int n = tid; n < NN; n += 256) mo += (gx[n] < g);
    atomicAdd(&off_s, mo);
    __syncthreads();
    for (int n = tid; n < NN; n += 256) {
        if (gx[n] == g) {
            int pp = atomicAdd(&pos_s, 1);
            qperm[bh*NN + off_s + pp] = n;
        }
    }
    __syncthreads();
    if (tid == 0) { qoff[bid] = off_s; qcnt[bid] = pos_s; }
}

// ---------------------------------------------------------------------------
// Kernel 3b: scores[bh*GN+g][n] = qmean[bh,g] . k[bh,n]. Thread owns one n,
// k-row in registers, qmean tile in LDS (broadcast reads), coalesced stores.
// ---------------------------------------------------------------------------
__global__ __launch_bounds__(256)
void score_all(const float* __restrict__ qmean, const float* __restrict__ k,
               float* __restrict__ scores)
{
    __shared__ float Qs[GN][HD];          // 6 KB
    const int bh = blockIdx.y;
    const int tid = threadIdx.x;
    const int n = blockIdx.x*256 + tid;
    for (int i = tid; i < GN*HD; i += 256)
        ((float*)Qs)[i] = qmean[bh*GN*HD + i];
    __syncthreads();
    if (n >= NN) return;
    const float* __restrict__ kp = k + (bh*NN + n)*HD;
    float4 kr[8];
    #pragma unroll
    for (int c = 0; c < 8; ++c) kr[c] = *(const float4*)&kp[c*4];
    for (int g = 0; g < GN; ++g) {
        float s = 0.f;
        #pragma unroll
        for (int c = 0; c < 8; ++c) {
            float4 qv = *(const float4*)&Qs[g][c*4];   // same-addr broadcast
            s += kr[c].x*qv.x + kr[c].y*qv.y + kr[c].z*qv.z + kr[c].w*qv.w;
        }
        scores[(bh*GN + g)*NN + n] = s;               // coalesced per g
    }
}

// ---------------------------------------------------------------------------
// Kernel 3c: per-WAVE barrier-free radix top-96. Each 64-lane wave owns one
// (bh,g) row of 1600 scores: keys + 256-bin hist live in per-wave LDS slices
// (DS ops from a wave complete in program order -> no __syncthreads).
// Suffix-scan in registers via shfl; pivot via ballot; collect via ballot-
// compaction in ascending index order (== lax.top_k lowest-index ties).
// ---------------------------------------------------------------------------
__global__ __launch_bounds__(256)
void topk_radix(const float* __restrict__ scores, int* __restrict__ topk)
{
    __shared__ unsigned keysL[4][NN];     // 25.6 KB
    __shared__ unsigned histL[4][256];    // 4 KB
    const int tid = threadIdx.x;
    const int w = tid >> 6, lane = tid & 63;
    const int gid = blockIdx.x*4 + w;     // (bh*GN + g) in [0,1152)
    const float* __restrict__ row = scores + gid*NN;
    unsigned* keys = keysL[w];
    unsigned* hist = histL[w];

    // load + order-preserving transform (1600 = 25*64 exactly)
    #pragma unroll
    for (int i = 0; i < 25; ++i) {
        int m = lane + 64*i;
        unsigned u = __float_as_uint(row[m]);
        u = (u & 0x80000000u) ? ~u : (u | 0x80000000u);
        keys[m] = u;
    }

    unsigned prefix = 0, r = TK;
    #pragma unroll
    for (int pass = 0; pass < 4; ++pass) {
        const int shift = 24 - 8*pass;
        #pragma unroll
        for (int j = 0; j < 4; ++j) hist[lane*4 + j] = 0;
        #pragma unroll
        for (int i = 0; i < 25; ++i) {
            unsigned u = keys[lane + 64*i];
            bool match = (pass == 0) || ((u >> (shift+8)) == (prefix >> (shift+8)));
            if (match) atomicAdd(&hist[(u >> shift) & 255u], 1u);
        }
        // suffix scan: lane holds bins 4L..4L+3
        uint4 h = *(const uint4*)&hist[lane*4];
        unsigned s3 = h.w, s2 = h.z + s3, s1 = h.y + s2, s0 = h.x + s1;
        unsigned I = s0;                      // inclusive suffix over lane totals
        #pragma unroll
        for (int off = 1; off < 64; off <<= 1) {
            unsigned t = __shfl_down(I, off);
            if (lane + off < 64) I += t;
        }
        unsigned E = I - s0;                  // strict suffix (lanes > L)
        unsigned sf[5] = {E+s0, E+s1, E+s2, E+s3, E};
        int bj = -1; unsigned subc = 0;
        #pragma unroll
        for (int j = 0; j < 4; ++j)
            if (sf[j] >= r && sf[j+1] < r) { bj = j; subc = sf[j+1]; }
        unsigned long long mask = __ballot(bj >= 0);   // exactly one bit set
        int src = __ffsll(mask) - 1;
        int bstar = __shfl(lane*4 + bj, src);
        unsigned sub = (unsigned)__shfl((int)subc, src);
        prefix |= ((unsigned)bstar) << shift;
        r -= sub;
    }
    const unsigned P = prefix;   // exact 96th-largest key; r = #equals to take

    // collect: all keys > P, then first r keys == P (ascending index)
    int* tko = topk + gid*TK;
    int base = 0;
    #pragma unroll
    for (int i = 0; i < 25; ++i) {
        int m = lane + 64*i;
        bool gt = (keys[m] > P);
        unsigned long long mask = __ballot(gt);
        if (gt) tko[base + __popcll(mask & ((1ull << lane) - 1ull))] = m;
        base += (int)__popcll(mask);
    }
    #pragma unroll
    for (int i = 0; i < 25; ++i) {
        int m = lane + 64*i;
        bool eq = (keys[m] == P);
        unsigned long long mask = __ballot(eq);
        if (eq) {
            int pos = base + (int)__popcll(mask & ((1ull << lane) - 1ull));
            if (pos < TK) tko[pos] = m;
        }
        base += (int)__popcll(mask);
    }
}

// ---------------------------------------------------------------------------
// Kernel 4 (v5b): group-bucketed attention, LDS-staged K/V, low-register
// inner loop. NO min-waves launch bound: the kernel's natural footprint is
// ~140 VGPR (v4 precedent); capping at 128 (256,4) caused scratch spills
// (WRITE_SIZE 4.8 -> 477 MB in round 8). VGPR-limited ~3 waves/SIMD is fine.
// ---------------------------------------------------------------------------
__global__ __launch_bounds__(256)
void sparse_attn5(const float* __restrict__ q, const float* __restrict__ k,
                  const float* __restrict__ v, const int* __restrict__ topk,
                  const int* __restrict__ qperm, const int* __restrict__ qoff,
                  const int* __restrict__ qcnt, float* __restrict__ out)
{
    __shared__ float Ks[TK*HD];   // 12 KB
    __shared__ float Vs[TK*HD];   // 12 KB

    const int bid = blockIdx.x;   // bh*GN + g
    const int bh = bid / GN;
    const int nq = qcnt[bid];
    if (nq == 0) return;          // uniform per block
    const int off = qoff[bid];
    const int tid = threadIdx.x;

    const int* __restrict__ tk = topk + bid*TK;
    const float* __restrict__ kb = k + bh*NN*HD;
    const float* __restrict__ vb = v + bh*NN*HD;

    // stage K,V: 768 float4 each; 8 consecutive lanes fetch one 128B row
    for (int idx = tid; idx < TK*8; idx += 256) {
        int row = idx >> 3, ch = idx & 7;
        int r = tk[row];
        ((float4*)Ks)[idx] = *(const float4*)&kb[r*HD + ch*4];
        ((float4*)Vs)[idx] = *(const float4*)&vb[r*HD + ch*4];
    }
    __syncthreads();

    const float scale = 0.17677669529663687f;   // 32^-0.5
    const int qs = tid >> 3;            // query slot 0..31
    const int dl = tid & 7;             // lane in 8-lane group
    const int lb = (tid & 63) & ~7;     // wave-lane base of the group
    const int b = bh / NH, hh = bh - b*NH;
    const float* __restrict__ qbase = q + bh*NN*HD;
    const int* __restrict__ qlist = qperm + bh*NN + off;

    for (int it0 = 0; it0 < nq; it0 += 32) {
        const int qi = it0 + qs;
        const bool act = (qi < nq);
        const int nn = qlist[act ? qi : nq-1];   // whole 8-lane group inactive together

        float4 q4 = *(const float4*)&qbase[nn*HD + dl*4];

        // phase 1: lane dl owns keys t*8+dl; per key all 8 lanes cooperate
        float sc[12];
        #pragma unroll
        for (int t = 0; t < 12; ++t) {
            float keep = 0.f;
            #pragma unroll
            for (int u = 0; u < 8; ++u) {
                float4 w = *(const float4*)&Ks[(t*8 + u)*HD + dl*4];
                float p = fmaf(q4.x, w.x, fmaf(q4.y, w.y, fmaf(q4.z, w.z, q4.w*w.w)));
                p += __shfl_xor(p, 1);
                p += __shfl_xor(p, 2);
                p += __shfl_xor(p, 4);
                if (u == dl) keep = p;
            }
            sc[t] = keep * scale;
        }

        // softmax across the 96 scores (8-lane shfl reduce)
        float m = -INFINITY;
        #pragma unroll
        for (int t = 0; t < 12; ++t) m = fmaxf(m, sc[t]);
        #pragma unroll
        for (int o = 1; o < 8; o <<= 1) m = fmaxf(m, __shfl_xor(m, o));
        float l = 0.f;
        #pragma unroll
        for (int t = 0; t < 12; ++t) { sc[t] = __expf(sc[t] - m); l += sc[t]; }
        #pragma unroll
        for (int o = 1; o < 8; o <<= 1) l += __shfl_xor(l, o);
        const float inv = 1.0f / l;
        #pragma unroll
        for (int t = 0; t < 12; ++t) sc[t] *= inv;

        // phase 2: weighted V sum; lane owns dims 4dl..4dl+3 (LDS broadcast)
        float a0 = 0.f, a1 = 0.f, a2 = 0.f, a3 = 0.f;
        #pragma unroll
        for (int t = 0; t < 12; ++t) {
            #pragma unroll
            for (int u = 0; u < 8; ++u) {
                const float p = __shfl(sc[t], lb + u);
                float4 vv = *(const float4*)&Vs[(t*8 + u)*HD + dl*4];
                a0 = fmaf(p, vv.x, a0);
                a1 = fmaf(p, vv.y, a1);
                a2 = fmaf(p, vv.z, a2);
                a3 = fmaf(p, vv.w, a3);
            }
        }

        if (act) {
            float* op = out + (b*NN + nn)*CC + hh*HD + dl*4;
            *(float4*)op = make_float4(a0, a1, a2, a3);
        }
    }
}

// ---------------------------------------------------------------------------
extern "C" void kernel_launch(void* const* d_in, const int* in_sizes, int n_in,
                              void* d_out, int out_size, void* d_ws, size_t ws_size,
                              hipStream_t stream)
{
    const float* x      = (const float*)d_in[0];   // [B,H,W,C] = [3200, 384]
    const float* w_qkv  = (const float*)d_in[1];   // [1152, 384]
    const float* w_gp   = (const float*)d_in[2];   // [48, 384] -> (12,48,32)
    const float* w_proj = (const float*)d_in[3];   // [384, 384]
    float* out = (float*)d_out;                    // [B,H,W,C]

    float* ws = (float*)d_ws;
    float* q        = ws;                 // [B,h,N,d] 1228800
    float* kk       = ws + 1228800;
    float* vv       = ws + 2457600;
    float* attn_out = ws + 3686400;       // [B,N,h*d] 1228800
    float* scores   = ws + 4915200;       // [1152][1600] 1843200
    float* qmean    = ws + 6758400;       // [1152][32]   36864
    int*   iws      = (int*)(ws + 6795264);
    int*   gidx     = iws;                // 38400
    int*   topk     = iws + 38400;        // 110592
    int*   qperm    = iws + 38400 + 110592;            // 38400
    int*   qoff     = iws + 38400 + 110592 + 38400;    // 1152
    int*   qcnt     = qoff + 1152;                     // 1152

    // 1) QKV projection, scatter into q/k/v
    gemm_tile<0><<<dim3(QKV_COLS/64, (NB*NN)/64), 256, 0, stream>>>(
        x, w_qkv, q, kk, vv, NB*NN, QKV_COLS, CC);

    // 2) query -> group routing
    group_route<<<NQ/256, 256, 0, stream>>>(q, w_gp, gidx);

    // 3a) deterministic group means + query buckets (1152 blocks)
    qmean_all2<<<BHN*GN, 256, 0, stream>>>(q, gidx, qmean, qperm, qoff, qcnt);

    // 3b) group->key score matrix
    score_all<<<dim3(7, BHN), 256, 0, stream>>>(qmean, kk, scores);

    // 3c) per-wave barrier-free radix top-96
    topk_radix<<<(BHN*GN)/4, 256, 0, stream>>>(scores, topk);

    // 4) group-bucketed sparse attention (K/V in LDS, natural VGPR budget)
    sparse_attn5<<<BHN*GN, 256, 0, stream>>>(q, kk, vv, topk, qperm, qoff, qcnt, attn_out);

    // 5) output projection
    gemm_tile<1><<<dim3(CC/64, (NB*NN)/64), 256, 0, stream>>>(
        attn_out, w_proj, out, nullptr, nullptr, NB*NN, CC, CC);
}

// Round 10
// 314.006 us; speedup vs baseline: 1.8648x; 1.2726x over previous
//
#include <hip/hip_runtime.h>
#include <math.h>

#define NH 12
#define HD 32
#define GN 48
#define TK 96
#define NB 2
#define NN 1600
#define CC 384
#define BHN (NB*NH)          // 24
#define QKV_COLS (3*NH*HD)   // 1152
#define NQ (BHN*NN)          // 38400 total (b,h,n) queries

// ---------------------------------------------------------------------------
// GEMM: out = A[M,K] @ B[N,K]^T   (both row-major; B rows are output cols)
// MODE 0: scatter epilogue into q/k/v [B,h,N,d]   MODE 1: plain store [M,N]
// ---------------------------------------------------------------------------
template<int MODE>
__global__ __launch_bounds__(256)
void gemm_tile(const float* __restrict__ A, const float* __restrict__ B,
               float* __restrict__ o0, float* __restrict__ o1, float* __restrict__ o2,
               int M, int N, int K)
{
    __shared__ float As[16][64];
    __shared__ float Bs[16][64];
    const int tid = threadIdx.x;
    const int tx = tid & 15, ty = tid >> 4;
    const int m0 = blockIdx.y * 64, n0 = blockIdx.x * 64;
    const int lr = tid >> 2;          // tile row 0..63
    const int lc = (tid & 3) * 4;     // k-seg 0,4,8,12
    float acc[4][4] = {};

    for (int k0 = 0; k0 < K; k0 += 16) {
        float4 av = *(const float4*)&A[(m0 + lr) * K + k0 + lc];
        float4 bv = *(const float4*)&B[(n0 + lr) * K + k0 + lc];
        __syncthreads();   // previous iter's compute done before overwrite
        As[lc+0][lr] = av.x; As[lc+1][lr] = av.y; As[lc+2][lr] = av.z; As[lc+3][lr] = av.w;
        Bs[lc+0][lr] = bv.x; Bs[lc+1][lr] = bv.y; Bs[lc+2][lr] = bv.z; Bs[lc+3][lr] = bv.w;
        __syncthreads();
        #pragma unroll
        for (int kk = 0; kk < 16; ++kk) {
            float4 a4 = *(const float4*)&As[kk][ty*4];
            float4 b4 = *(const float4*)&Bs[kk][tx*4];
            float a[4] = {a4.x, a4.y, a4.z, a4.w};
            float b[4] = {b4.x, b4.y, b4.z, b4.w};
            #pragma unroll
            for (int i = 0; i < 4; ++i)
                #pragma unroll
                for (int j = 0; j < 4; ++j)
                    acc[i][j] = fmaf(a[i], b[j], acc[i][j]);
        }
    }

    if (MODE == 0) {
        #pragma unroll
        for (int i = 0; i < 4; ++i) {
            int row = m0 + ty*4 + i;
            int b  = row / NN;
            int nn = row - b * NN;
            #pragma unroll
            for (int j = 0; j < 4; ++j) {
                int col = n0 + tx*4 + j;
                int which = col / CC;          // uniform per tile (384 % 64 == 0)
                int rem = col - which * CC;
                int hh = rem >> 5, dd = rem & 31;
                float* dst = (which == 0) ? o0 : (which == 1) ? o1 : o2;
                dst[((b*NH + hh)*NN + nn)*HD + dd] = acc[i][j];
            }
        }
    } else {
        #pragma unroll
        for (int i = 0; i < 4; ++i) {
            int row = m0 + ty*4 + i;
            float4 st = make_float4(acc[i][0], acc[i][1], acc[i][2], acc[i][3]);
            *(float4*)&o0[row * N + n0 + tx*4] = st;
        }
    }
}

// ---------------------------------------------------------------------------
// Kernel 2: per-query group argmax (gidx), strict > == jnp.argmax tie-break
// ---------------------------------------------------------------------------
__global__ __launch_bounds__(256)
void group_route(const float* __restrict__ q, const float* __restrict__ wgp,
                 int* __restrict__ gidx)
{
    int t = blockIdx.x * 256 + threadIdx.x;   // [0, NQ)
    int bh = t / NN;
    int hh = bh % NH;
    const float* qp = q + t * HD;
    float qr[HD];
    #pragma unroll
    for (int i = 0; i < HD; i += 4) {
        float4 x = *(const float4*)&qp[i];
        qr[i] = x.x; qr[i+1] = x.y; qr[i+2] = x.z; qr[i+3] = x.w;
    }
    float best = -INFINITY; int bg = 0;
    for (int g = 0; g < GN; ++g) {
        const float* gp = wgp + hh*GN*HD + g*HD;
        float s = 0.f;
        #pragma unroll
        for (int i = 0; i < HD; i += 4) {
            float4 w = *(const float4*)&gp[i];
            s += qr[i]*w.x + qr[i+1]*w.y + qr[i+2]*w.z + qr[i+3]*w.w;
        }
        if (s > best) { best = s; bg = g; }
    }
    gidx[t] = bg;
}

// ---------------------------------------------------------------------------
// Kernel 3a (v3): per-(bh,g) deterministic group-mean (register accumulation,
// round-1 summation order) + query bucketing (qperm/qoff/qcnt) for attention.
// 1152 blocks.
// ---------------------------------------------------------------------------
__global__ __launch_bounds__(256)
void qmean_all2(const float* __restrict__ q, const int* __restrict__ gidx,
                float* __restrict__ qmean, int* __restrict__ qperm,
                int* __restrict__ qoff, int* __restrict__ qcnt)
{
    __shared__ float part[8][HD];
    __shared__ int   cnts[8];
    __shared__ int   off_s, pos_s;
    const int bid = blockIdx.x;       // bh*GN + g
    const int g = bid % GN, bh = bid / GN;
    const int tid = threadIdx.x;
    const int s = tid >> 5, dd = tid & 31;

    const int* __restrict__ gx = gidx + bh*NN;
    const float* __restrict__ qb = q + bh*NN*HD;

    if (tid == 0) { off_s = 0; pos_s = 0; }

    float p = 0.f; int c = 0;
    for (int n = s; n < NN; n += 8) {
        if (gx[n] == g) { p += qb[n*HD + dd]; c++; }
    }
    part[s][dd] = p;
    if (dd == 0) cnts[s] = c;
    __syncthreads();                  // part[] + off_s/pos_s init visible

    if (tid < HD) {
        float sum = 0.f; int ct = 0;
        #pragma unroll
        for (int ss = 0; ss < 8; ++ss) { sum += part[ss][tid]; ct += cnts[ss]; }
        qmean[bid*HD + tid] = ct ? sum / (float)ct : 0.f;
    }

    // bucketing: offset = #queries in groups < g (gx row is L1-hot now)
    int mo = 0;
    for (int n = tid; n < NN; n += 256) mo += (gx[n] < g);
    atomicAdd(&off_s, mo);
    __syncthreads();
    for (int n = tid; n < NN; n += 256) {
        if (gx[n] == g) {
            int pp = atomicAdd(&pos_s, 1);
            qperm[bh*NN + off_s + pp] = n;
        }
    }
    __syncthreads();
    if (tid == 0) { qoff[bid] = off_s; qcnt[bid] = pos_s; }
}

// ---------------------------------------------------------------------------
// Kernel 3b: scores[bh*GN+g][n] = qmean[bh,g] . k[bh,n]. Thread owns one n,
// k-row in registers, qmean tile in LDS (broadcast reads), coalesced stores.
// ---------------------------------------------------------------------------
__global__ __launch_bounds__(256)
void score_all(const float* __restrict__ qmean, const float* __restrict__ k,
               float* __restrict__ scores)
{
    __shared__ float Qs[GN][HD];          // 6 KB
    const int bh = blockIdx.y;
    const int tid = threadIdx.x;
    const int n = blockIdx.x*256 + tid;
    for (int i = tid; i < GN*HD; i += 256)
        ((float*)Qs)[i] = qmean[bh*GN*HD + i];
    __syncthreads();
    if (n >= NN) return;
    const float* __restrict__ kp = k + (bh*NN + n)*HD;
    float4 kr[8];
    #pragma unroll
    for (int c = 0; c < 8; ++c) kr[c] = *(const float4*)&kp[c*4];
    for (int g = 0; g < GN; ++g) {
        float s = 0.f;
        #pragma unroll
        for (int c = 0; c < 8; ++c) {
            float4 qv = *(const float4*)&Qs[g][c*4];   // same-addr broadcast
            s += kr[c].x*qv.x + kr[c].y*qv.y + kr[c].z*qv.z + kr[c].w*qv.w;
        }
        scores[(bh*GN + g)*NN + n] = s;               // coalesced per g
    }
}

// ---------------------------------------------------------------------------
// Kernel 3c: per-WAVE barrier-free radix top-96. Each 64-lane wave owns one
// (bh,g) row of 1600 scores: keys + 256-bin hist live in per-wave LDS slices
// (DS ops from a wave complete in program order -> no __syncthreads).
// Suffix-scan in registers via shfl; pivot via ballot; collect via ballot-
// compaction in ascending index order (== lax.top_k lowest-index ties).
// ---------------------------------------------------------------------------
__global__ __launch_bounds__(256)
void topk_radix(const float* __restrict__ scores, int* __restrict__ topk)
{
    __shared__ unsigned keysL[4][NN];     // 25.6 KB
    __shared__ unsigned histL[4][256];    // 4 KB
    const int tid = threadIdx.x;
    const int w = tid >> 6, lane = tid & 63;
    const int gid = blockIdx.x*4 + w;     // (bh*GN + g) in [0,1152)
    const float* __restrict__ row = scores + gid*NN;
    unsigned* keys = keysL[w];
    unsigned* hist = histL[w];

    // load + order-preserving transform (1600 = 25*64 exactly)
    #pragma unroll
    for (int i = 0; i < 25; ++i) {
        int m = lane + 64*i;
        unsigned u = __float_as_uint(row[m]);
        u = (u & 0x80000000u) ? ~u : (u | 0x80000000u);
        keys[m] = u;
    }

    unsigned prefix = 0, r = TK;
    #pragma unroll
    for (int pass = 0; pass < 4; ++pass) {
        const int shift = 24 - 8*pass;
        #pragma unroll
        for (int j = 0; j < 4; ++j) hist[lane*4 + j] = 0;
        #pragma unroll
        for (int i = 0; i < 25; ++i) {
            unsigned u = keys[lane + 64*i];
            bool match = (pass == 0) || ((u >> (shift+8)) == (prefix >> (shift+8)));
            if (match) atomicAdd(&hist[(u >> shift) & 255u], 1u);
        }
        // suffix scan: lane holds bins 4L..4L+3
        uint4 h = *(const uint4*)&hist[lane*4];
        unsigned s3 = h.w, s2 = h.z + s3, s1 = h.y + s2, s0 = h.x + s1;
        unsigned I = s0;                      // inclusive suffix over lane totals
        #pragma unroll
        for (int off = 1; off < 64; off <<= 1) {
            unsigned t = __shfl_down(I, off);
            if (lane + off < 64) I += t;
        }
        unsigned E = I - s0;                  // strict suffix (lanes > L)
        unsigned sf[5] = {E+s0, E+s1, E+s2, E+s3, E};
        int bj = -1; unsigned subc = 0;
        #pragma unroll
        for (int j = 0; j < 4; ++j)
            if (sf[j] >= r && sf[j+1] < r) { bj = j; subc = sf[j+1]; }
        unsigned long long mask = __ballot(bj >= 0);   // exactly one bit set
        int src = __ffsll(mask) - 1;
        int bstar = __shfl(lane*4 + bj, src);
        unsigned sub = (unsigned)__shfl((int)subc, src);
        prefix |= ((unsigned)bstar) << shift;
        r -= sub;
    }
    const unsigned P = prefix;   // exact 96th-largest key; r = #equals to take

    // collect: all keys > P, then first r keys == P (ascending index)
    int* tko = topk + gid*TK;
    int base = 0;
    #pragma unroll
    for (int i = 0; i < 25; ++i) {
        int m = lane + 64*i;
        bool gt = (keys[m] > P);
        unsigned long long mask = __ballot(gt);
        if (gt) tko[base + __popcll(mask & ((1ull << lane) - 1ull))] = m;
        base += (int)__popcll(mask);
    }
    #pragma unroll
    for (int i = 0; i < 25; ++i) {
        int m = lane + 64*i;
        bool eq = (keys[m] == P);
        unsigned long long mask = __ballot(eq);
        if (eq) {
            int pos = base + (int)__popcll(mask & ((1ull << lane) - 1ull));
            if (pos < TK) tko[pos] = m;
        }
        base += (int)__popcll(mask);
    }
}

// ---------------------------------------------------------------------------
// Kernel 4 (v6): group-bucketed attention, LDS-staged K/V, register-array-free.
// Anti-hoisting design (round-9 lesson: statically-addressed LDS loads get
// hoisted en masse -> VGPR 256 + spills): phase-1 t-loop capped at unroll 2,
// raw scores go to an LDS buffer Ps (not a register array), phase 2 reads
// probs from Ps via 8-lane broadcast (no shuffles at all in phase 2).
// Ps padded to 104 floats/row: bank = (8*qs + j) % 32 -> worst 2-way (free).
// Per-thread live state: q4 + acc4 + m/l (~40 VGPR target).
// ---------------------------------------------------------------------------
__global__ __launch_bounds__(256)
void sparse_attn6(const float* __restrict__ q, const float* __restrict__ k,
                  const float* __restrict__ v, const int* __restrict__ topk,
                  const int* __restrict__ qperm, const int* __restrict__ qoff,
                  const int* __restrict__ qcnt, float* __restrict__ out)
{
    __shared__ float Ks[TK*HD];      // 12 KB
    __shared__ float Vs[TK*HD];      // 12 KB
    __shared__ float Ps[32][104];    // 13.3 KB, padded row (104%32==8)

    const int bid = blockIdx.x;   // bh*GN + g
    const int bh = bid / GN;
    const int nq = qcnt[bid];
    if (nq == 0) return;          // uniform per block
    const int off = qoff[bid];
    const int tid = threadIdx.x;

    const int* __restrict__ tk = topk + bid*TK;
    const float* __restrict__ kb = k + bh*NN*HD;
    const float* __restrict__ vb = v + bh*NN*HD;

    // stage K,V: 768 float4 each; 8 consecutive lanes fetch one 128B row
    for (int idx = tid; idx < TK*8; idx += 256) {
        int row = idx >> 3, ch = idx & 7;
        int r = tk[row];
        ((float4*)Ks)[idx] = *(const float4*)&kb[r*HD + ch*4];
        ((float4*)Vs)[idx] = *(const float4*)&vb[r*HD + ch*4];
    }
    __syncthreads();

    const float scale = 0.17677669529663687f;   // 32^-0.5
    const int qs = tid >> 3;            // query slot 0..31 (Ps row owner)
    const int dl = tid & 7;             // lane in 8-lane group
    const int b = bh / NH, hh = bh - b*NH;
    const float* __restrict__ qbase = q + bh*NN*HD;
    const int* __restrict__ qlist = qperm + bh*NN + off;

    for (int it0 = 0; it0 < nq; it0 += 32) {
        const int qi = it0 + qs;
        const bool act = (qi < nq);
        const int nn = qlist[act ? qi : nq-1];   // safe clamp; group-uniform

        float4 q4 = *(const float4*)&qbase[nn*HD + dl*4];

        // phase 1: raw scores -> Ps[qs][key]; lane dl owns keys t*8+dl.
        // unroll 2 caps in-flight LDS loads; Ps write has dynamic addr (LDS ok)
        #pragma unroll 2
        for (int t = 0; t < 12; ++t) {
            float keep = 0.f;
            #pragma unroll
            for (int u = 0; u < 8; ++u) {
                float4 w = *(const float4*)&Ks[(t*8 + u)*HD + dl*4];
                float p = fmaf(q4.x, w.x, fmaf(q4.y, w.y, fmaf(q4.z, w.z, q4.w*w.w)));
                p += __shfl_xor(p, 1);
                p += __shfl_xor(p, 2);
                p += __shfl_xor(p, 4);
                if (u == dl) keep = p;
            }
            Ps[qs][t*8 + dl] = keep * scale;   // wave-coherent, no barrier
        }

        // softmax over the 96 scores: re-read own 12 (static offsets)
        float raw[12];
        #pragma unroll
        for (int t = 0; t < 12; ++t) raw[t] = Ps[qs][t*8 + dl];
        float m = -INFINITY;
        #pragma unroll
        for (int t = 0; t < 12; ++t) m = fmaxf(m, raw[t]);
        #pragma unroll
        for (int o = 1; o < 8; o <<= 1) m = fmaxf(m, __shfl_xor(m, o));
        float l = 0.f;
        #pragma unroll
        for (int t = 0; t < 12; ++t) l += __expf(raw[t] - m);
        #pragma unroll
        for (int o = 1; o < 8; o <<= 1) l += __shfl_xor(l, o);
        const float inv = 1.0f / l;
        #pragma unroll
        for (int t = 0; t < 12; ++t) Ps[qs][t*8 + dl] = __expf(raw[t] - m) * inv;

        // phase 2: weighted V sum; p via LDS broadcast (no shuffles)
        float a0 = 0.f, a1 = 0.f, a2 = 0.f, a3 = 0.f;
        #pragma unroll 4
        for (int j = 0; j < TK; ++j) {
            const float p = Ps[qs][j];                       // 8-lane broadcast
            float4 vv = *(const float4*)&Vs[j*HD + dl*4];    // bcast across groups
            a0 = fmaf(p, vv.x, a0);
            a1 = fmaf(p, vv.y, a1);
            a2 = fmaf(p, vv.z, a2);
            a3 = fmaf(p, vv.w, a3);
        }

        if (act) {
            float* op = out + (b*NN + nn)*CC + hh*HD + dl*4;
            *(float4*)op = make_float4(a0, a1, a2, a3);
        }
    }
}

// ---------------------------------------------------------------------------
extern "C" void kernel_launch(void* const* d_in, const int* in_sizes, int n_in,
                              void* d_out, int out_size, void* d_ws, size_t ws_size,
                              hipStream_t stream)
{
    const float* x      = (const float*)d_in[0];   // [B,H,W,C] = [3200, 384]
    const float* w_qkv  = (const float*)d_in[1];   // [1152, 384]
    const float* w_gp   = (const float*)d_in[2];   // [48, 384] -> (12,48,32)
    const float* w_proj = (const float*)d_in[3];   // [384, 384]
    float* out = (float*)d_out;                    // [B,H,W,C]

    float* ws = (float*)d_ws;
    float* q        = ws;                 // [B,h,N,d] 1228800
    float* kk       = ws + 1228800;
    float* vv       = ws + 2457600;
    float* attn_out = ws + 3686400;       // [B,N,h*d] 1228800
    float* scores   = ws + 4915200;       // [1152][1600] 1843200
    float* qmean    = ws + 6758400;       // [1152][32]   36864
    int*   iws      = (int*)(ws + 6795264);
    int*   gidx     = iws;                // 38400
    int*   topk     = iws + 38400;        // 110592
    int*   qperm    = iws + 38400 + 110592;            // 38400
    int*   qoff     = iws + 38400 + 110592 + 38400;    // 1152
    int*   qcnt     = qoff + 1152;                     // 1152

    // 1) QKV projection, scatter into q/k/v
    gemm_tile<0><<<dim3(QKV_COLS/64, (NB*NN)/64), 256, 0, stream>>>(
        x, w_qkv, q, kk, vv, NB*NN, QKV_COLS, CC);

    // 2) query -> group routing
    group_route<<<NQ/256, 256, 0, stream>>>(q, w_gp, gidx);

    // 3a) deterministic group means + query buckets (1152 blocks)
    qmean_all2<<<BHN*GN, 256, 0, stream>>>(q, gidx, qmean, qperm, qoff, qcnt);

    // 3b) group->key score matrix
    score_all<<<dim3(7, BHN), 256, 0, stream>>>(qmean, kk, scores);

    // 3c) per-wave barrier-free radix top-96
    topk_radix<<<(BHN*GN)/4, 256, 0, stream>>>(scores, topk);

    // 4) group-bucketed sparse attention (LDS K/V + LDS score buffer)
    sparse_attn6<<<BHN*GN, 256, 0, stream>>>(q, kk, vv, topk, qperm, qoff, qcnt, attn_out);

    // 5) output projection
    gemm_tile<1><<<dim3(CC/64, (NB*NN)/64), 256, 0, stream>>>(
        attn_out, w_proj, out, nullptr, nullptr, NB*NN, CC, CC);
}

// Round 11
// 310.323 us; speedup vs baseline: 1.8869x; 1.0119x over previous
//
#include <hip/hip_runtime.h>
#include <math.h>

#define NH 12
#define HD 32
#define GN 48
#define TK 96
#define NB 2
#define NN 1600
#define CC 384
#define BHN (NB*NH)          // 24
#define QKV_COLS (3*NH*HD)   // 1152
#define NQ (BHN*NN)          // 38400 total (b,h,n) queries

// ---------------------------------------------------------------------------
// GEMM: out = A[M,K] @ B[N,K]^T   (both row-major; B rows are output cols)
// MODE 0: scatter epilogue into q/k/v [B,h,N,d]   MODE 1: plain store [M,N]
// ---------------------------------------------------------------------------
template<int MODE>
__global__ __launch_bounds__(256)
void gemm_tile(const float* __restrict__ A, const float* __restrict__ B,
               float* __restrict__ o0, float* __restrict__ o1, float* __restrict__ o2,
               int M, int N, int K)
{
    __shared__ float As[16][64];
    __shared__ float Bs[16][64];
    const int tid = threadIdx.x;
    const int tx = tid & 15, ty = tid >> 4;
    const int m0 = blockIdx.y * 64, n0 = blockIdx.x * 64;
    const int lr = tid >> 2;          // tile row 0..63
    const int lc = (tid & 3) * 4;     // k-seg 0,4,8,12
    float acc[4][4] = {};

    for (int k0 = 0; k0 < K; k0 += 16) {
        float4 av = *(const float4*)&A[(m0 + lr) * K + k0 + lc];
        float4 bv = *(const float4*)&B[(n0 + lr) * K + k0 + lc];
        __syncthreads();   // previous iter's compute done before overwrite
        As[lc+0][lr] = av.x; As[lc+1][lr] = av.y; As[lc+2][lr] = av.z; As[lc+3][lr] = av.w;
        Bs[lc+0][lr] = bv.x; Bs[lc+1][lr] = bv.y; Bs[lc+2][lr] = bv.z; Bs[lc+3][lr] = bv.w;
        __syncthreads();
        #pragma unroll
        for (int kk = 0; kk < 16; ++kk) {
            float4 a4 = *(const float4*)&As[kk][ty*4];
            float4 b4 = *(const float4*)&Bs[kk][tx*4];
            float a[4] = {a4.x, a4.y, a4.z, a4.w};
            float b[4] = {b4.x, b4.y, b4.z, b4.w};
            #pragma unroll
            for (int i = 0; i < 4; ++i)
                #pragma unroll
                for (int j = 0; j < 4; ++j)
                    acc[i][j] = fmaf(a[i], b[j], acc[i][j]);
        }
    }

    if (MODE == 0) {
        #pragma unroll
        for (int i = 0; i < 4; ++i) {
            int row = m0 + ty*4 + i;
            int b  = row / NN;
            int nn = row - b * NN;
            #pragma unroll
            for (int j = 0; j < 4; ++j) {
                int col = n0 + tx*4 + j;
                int which = col / CC;          // uniform per tile (384 % 64 == 0)
                int rem = col - which * CC;
                int hh = rem >> 5, dd = rem & 31;
                float* dst = (which == 0) ? o0 : (which == 1) ? o1 : o2;
                dst[((b*NH + hh)*NN + nn)*HD + dd] = acc[i][j];
            }
        }
    } else {
        #pragma unroll
        for (int i = 0; i < 4; ++i) {
            int row = m0 + ty*4 + i;
            float4 st = make_float4(acc[i][0], acc[i][1], acc[i][2], acc[i][3]);
            *(float4*)&o0[row * N + n0 + tx*4] = st;
        }
    }
}

// ---------------------------------------------------------------------------
// Kernel 2: per-query group argmax (gidx), strict > == jnp.argmax tie-break
// ---------------------------------------------------------------------------
__global__ __launch_bounds__(256)
void group_route(const float* __restrict__ q, const float* __restrict__ wgp,
                 int* __restrict__ gidx)
{
    int t = blockIdx.x * 256 + threadIdx.x;   // [0, NQ)
    int bh = t / NN;
    int hh = bh % NH;
    const float* qp = q + t * HD;
    float qr[HD];
    #pragma unroll
    for (int i = 0; i < HD; i += 4) {
        float4 x = *(const float4*)&qp[i];
        qr[i] = x.x; qr[i+1] = x.y; qr[i+2] = x.z; qr[i+3] = x.w;
    }
    float best = -INFINITY; int bg = 0;
    for (int g = 0; g < GN; ++g) {
        const float* gp = wgp + hh*GN*HD + g*HD;
        float s = 0.f;
        #pragma unroll
        for (int i = 0; i < HD; i += 4) {
            float4 w = *(const float4*)&gp[i];
            s += qr[i]*w.x + qr[i+1]*w.y + qr[i+2]*w.z + qr[i+3]*w.w;
        }
        if (s > best) { best = s; bg = g; }
    }
    gidx[t] = bg;
}

// ---------------------------------------------------------------------------
// Kernel 3a (v3): per-(bh,g) deterministic group-mean (register accumulation,
// round-1 summation order) + query bucketing (qperm/qoff/qcnt) for attention.
// 1152 blocks.
// ---------------------------------------------------------------------------
__global__ __launch_bounds__(256)
void qmean_all2(const float* __restrict__ q, const int* __restrict__ gidx,
                float* __restrict__ qmean, int* __restrict__ qperm,
                int* __restrict__ qoff, int* __restrict__ qcnt)
{
    __shared__ float part[8][HD];
    __shared__ int   cnts[8];
    __shared__ int   off_s, pos_s;
    const int bid = blockIdx.x;       // bh*GN + g
    const int g = bid % GN, bh = bid / GN;
    const int tid = threadIdx.x;
    const int s = tid >> 5, dd = tid & 31;

    const int* __restrict__ gx = gidx + bh*NN;
    const float* __restrict__ qb = q + bh*NN*HD;

    if (tid == 0) { off_s = 0; pos_s = 0; }

    float p = 0.f; int c = 0;
    for (int n = s; n < NN; n += 8) {
        if (gx[n] == g) { p += qb[n*HD + dd]; c++; }
    }
    part[s][dd] = p;
    if (dd == 0) cnts[s] = c;
    __syncthreads();                  // part[] + off_s/pos_s init visible

    if (tid < HD) {
        float sum = 0.f; int ct = 0;
        #pragma unroll
        for (int ss = 0; ss < 8; ++ss) { sum += part[ss][tid]; ct += cnts[ss]; }
        qmean[bid*HD + tid] = ct ? sum / (float)ct : 0.f;
    }

    // bucketing: offset = #queries in groups < g (gx row is L1-hot now)
    int mo = 0;
    for (int n = tid; n < NN; n += 256) mo += (gx[n] < g);
    atomicAdd(&off_s, mo);
    __syncthreads();
    for (int n = tid; n < NN; n += 256) {
        if (gx[n] == g) {
            int pp = atomicAdd(&pos_s, 1);
            qperm[bh*NN + off_s + pp] = n;
        }
    }
    __syncthreads();
    if (tid == 0) { qoff[bid] = off_s; qcnt[bid] = pos_s; }
}

// ---------------------------------------------------------------------------
// Kernel 3b: scores[bh*GN+g][n] = qmean[bh,g] . k[bh,n]. Thread owns one n,
// k-row in registers, qmean tile in LDS (broadcast reads), coalesced stores.
// ---------------------------------------------------------------------------
__global__ __launch_bounds__(256)
void score_all(const float* __restrict__ qmean, const float* __restrict__ k,
               float* __restrict__ scores)
{
    __shared__ float Qs[GN][HD];          // 6 KB
    const int bh = blockIdx.y;
    const int tid = threadIdx.x;
    const int n = blockIdx.x*256 + tid;
    for (int i = tid; i < GN*HD; i += 256)
        ((float*)Qs)[i] = qmean[bh*GN*HD + i];
    __syncthreads();
    if (n >= NN) return;
    const float* __restrict__ kp = k + (bh*NN + n)*HD;
    float4 kr[8];
    #pragma unroll
    for (int c = 0; c < 8; ++c) kr[c] = *(const float4*)&kp[c*4];
    for (int g = 0; g < GN; ++g) {
        float s = 0.f;
        #pragma unroll
        for (int c = 0; c < 8; ++c) {
            float4 qv = *(const float4*)&Qs[g][c*4];   // same-addr broadcast
            s += kr[c].x*qv.x + kr[c].y*qv.y + kr[c].z*qv.z + kr[c].w*qv.w;
        }
        scores[(bh*GN + g)*NN + n] = s;               // coalesced per g
    }
}

// ---------------------------------------------------------------------------
// Kernel 3c: per-WAVE barrier-free radix top-96. Each 64-lane wave owns one
// (bh,g) row of 1600 scores: keys + 256-bin hist live in per-wave LDS slices
// (DS ops from a wave complete in program order -> no __syncthreads).
// Suffix-scan in registers via shfl; pivot via ballot; collect via ballot-
// compaction in ascending index order (== lax.top_k lowest-index ties).
// ---------------------------------------------------------------------------
__global__ __launch_bounds__(256)
void topk_radix(const float* __restrict__ scores, int* __restrict__ topk)
{
    __shared__ unsigned keysL[4][NN];     // 25.6 KB
    __shared__ unsigned histL[4][256];    // 4 KB
    const int tid = threadIdx.x;
    const int w = tid >> 6, lane = tid & 63;
    const int gid = blockIdx.x*4 + w;     // (bh*GN + g) in [0,1152)
    const float* __restrict__ row = scores + gid*NN;
    unsigned* keys = keysL[w];
    unsigned* hist = histL[w];

    // load + order-preserving transform (1600 = 25*64 exactly)
    #pragma unroll
    for (int i = 0; i < 25; ++i) {
        int m = lane + 64*i;
        unsigned u = __float_as_uint(row[m]);
        u = (u & 0x80000000u) ? ~u : (u | 0x80000000u);
        keys[m] = u;
    }

    unsigned prefix = 0, r = TK;
    #pragma unroll
    for (int pass = 0; pass < 4; ++pass) {
        const int shift = 24 - 8*pass;
        #pragma unroll
        for (int j = 0; j < 4; ++j) hist[lane*4 + j] = 0;
        #pragma unroll
        for (int i = 0; i < 25; ++i) {
            unsigned u = keys[lane + 64*i];
            bool match = (pass == 0) || ((u >> (shift+8)) == (prefix >> (shift+8)));
            if (match) atomicAdd(&hist[(u >> shift) & 255u], 1u);
        }
        // suffix scan: lane holds bins 4L..4L+3
        uint4 h = *(const uint4*)&hist[lane*4];
        unsigned s3 = h.w, s2 = h.z + s3, s1 = h.y + s2, s0 = h.x + s1;
        unsigned I = s0;                      // inclusive suffix over lane totals
        #pragma unroll
        for (int off = 1; off < 64; off <<= 1) {
            unsigned t = __shfl_down(I, off);
            if (lane + off < 64) I += t;
        }
        unsigned E = I - s0;                  // strict suffix (lanes > L)
        unsigned sf[5] = {E+s0, E+s1, E+s2, E+s3, E};
        int bj = -1; unsigned subc = 0;
        #pragma unroll
        for (int j = 0; j < 4; ++j)
            if (sf[j] >= r && sf[j+1] < r) { bj = j; subc = sf[j+1]; }
        unsigned long long mask = __ballot(bj >= 0);   // exactly one bit set
        int src = __ffsll(mask) - 1;
        int bstar = __shfl(lane*4 + bj, src);
        unsigned sub = (unsigned)__shfl((int)subc, src);
        prefix |= ((unsigned)bstar) << shift;
        r -= sub;
    }
    const unsigned P = prefix;   // exact 96th-largest key; r = #equals to take

    // collect: all keys > P, then first r keys == P (ascending index)
    int* tko = topk + gid*TK;
    int base = 0;
    #pragma unroll
    for (int i = 0; i < 25; ++i) {
        int m = lane + 64*i;
        bool gt = (keys[m] > P);
        unsigned long long mask = __ballot(gt);
        if (gt) tko[base + __popcll(mask & ((1ull << lane) - 1ull))] = m;
        base += (int)__popcll(mask);
    }
    #pragma unroll
    for (int i = 0; i < 25; ++i) {
        int m = lane + 64*i;
        bool eq = (keys[m] == P);
        unsigned long long mask = __ballot(eq);
        if (eq) {
            int pos = base + (int)__popcll(mask & ((1ull << lane) - 1ull));
            if (pos < TK) tko[pos] = m;
        }
        base += (int)__popcll(mask);
    }
}

// ---------------------------------------------------------------------------
// Kernel 4 (v7): v6 + split-S load balancing. TWO blocks per (bh,g); block
// sub in {0,1} handles 32-query chunks sub, sub+2, ... of the group bucket.
// Max per-block pass count ~halves (imbalance bounded at 1 pass). Inner loop
// identical to v6 (verified: VGPR 52, zero spill, zero bank conflicts).
// ---------------------------------------------------------------------------
__global__ __launch_bounds__(256)
void sparse_attn7(const float* __restrict__ q, const float* __restrict__ k,
                  const float* __restrict__ v, const int* __restrict__ topk,
                  const int* __restrict__ qperm, const int* __restrict__ qoff,
                  const int* __restrict__ qcnt, float* __restrict__ out)
{
    __shared__ float Ks[TK*HD];      // 12 KB
    __shared__ float Vs[TK*HD];      // 12 KB
    __shared__ float Ps[32][104];    // 13.3 KB, padded row (104%32==8)

    const int sub = blockIdx.x & 1;       // which half of the chunk sequence
    const int bid = blockIdx.x >> 1;      // bh*GN + g
    const int bh = bid / GN;
    const int nq = qcnt[bid];
    if (nq <= sub*32) return;             // this half has no work (uniform)
    const int off = qoff[bid];
    const int tid = threadIdx.x;

    const int* __restrict__ tk = topk + bid*TK;
    const float* __restrict__ kb = k + bh*NN*HD;
    const float* __restrict__ vb = v + bh*NN*HD;

    // stage K,V: 768 float4 each; 8 consecutive lanes fetch one 128B row
    for (int idx = tid; idx < TK*8; idx += 256) {
        int row = idx >> 3, ch = idx & 7;
        int r = tk[row];
        ((float4*)Ks)[idx] = *(const float4*)&kb[r*HD + ch*4];
        ((float4*)Vs)[idx] = *(const float4*)&vb[r*HD + ch*4];
    }
    __syncthreads();

    const float scale = 0.17677669529663687f;   // 32^-0.5
    const int qs = tid >> 3;            // query slot 0..31 (Ps row owner)
    const int dl = tid & 7;             // lane in 8-lane group
    const int b = bh / NH, hh = bh - b*NH;
    const float* __restrict__ qbase = q + bh*NN*HD;
    const int* __restrict__ qlist = qperm + bh*NN + off;

    for (int it0 = sub*32; it0 < nq; it0 += 64) {
        const int qi = it0 + qs;
        const bool act = (qi < nq);
        const int nn = qlist[act ? qi : nq-1];   // safe clamp; group-uniform

        float4 q4 = *(const float4*)&qbase[nn*HD + dl*4];

        // phase 1: raw scores -> Ps[qs][key]; lane dl owns keys t*8+dl.
        // unroll 2 caps in-flight LDS loads; Ps write has dynamic addr (LDS ok)
        #pragma unroll 2
        for (int t = 0; t < 12; ++t) {
            float keep = 0.f;
            #pragma unroll
            for (int u = 0; u < 8; ++u) {
                float4 w = *(const float4*)&Ks[(t*8 + u)*HD + dl*4];
                float p = fmaf(q4.x, w.x, fmaf(q4.y, w.y, fmaf(q4.z, w.z, q4.w*w.w)));
                p += __shfl_xor(p, 1);
                p += __shfl_xor(p, 2);
                p += __shfl_xor(p, 4);
                if (u == dl) keep = p;
            }
            Ps[qs][t*8 + dl] = keep * scale;   // wave-coherent, no barrier
        }

        // softmax over the 96 scores: re-read own 12 (static offsets)
        float raw[12];
        #pragma unroll
        for (int t = 0; t < 12; ++t) raw[t] = Ps[qs][t*8 + dl];
        float m = -INFINITY;
        #pragma unroll
        for (int t = 0; t < 12; ++t) m = fmaxf(m, raw[t]);
        #pragma unroll
        for (int o = 1; o < 8; o <<= 1) m = fmaxf(m, __shfl_xor(m, o));
        float l = 0.f;
        #pragma unroll
        for (int t = 0; t < 12; ++t) l += __expf(raw[t] - m);
        #pragma unroll
        for (int o = 1; o < 8; o <<= 1) l += __shfl_xor(l, o);
        const float inv = 1.0f / l;
        #pragma unroll
        for (int t = 0; t < 12; ++t) Ps[qs][t*8 + dl] = __expf(raw[t] - m) * inv;

        // phase 2: weighted V sum; p via LDS broadcast (no shuffles)
        float a0 = 0.f, a1 = 0.f, a2 = 0.f, a3 = 0.f;
        #pragma unroll 4
        for (int j = 0; j < TK; ++j) {
            const float p = Ps[qs][j];                       // 8-lane broadcast
            float4 vv = *(const float4*)&Vs[j*HD + dl*4];    // bcast across groups
            a0 = fmaf(p, vv.x, a0);
            a1 = fmaf(p, vv.y, a1);
            a2 = fmaf(p, vv.z, a2);
            a3 = fmaf(p, vv.w, a3);
        }

        if (act) {
            float* op = out + (b*NN + nn)*CC + hh*HD + dl*4;
            *(float4*)op = make_float4(a0, a1, a2, a3);
        }
    }
}

// ---------------------------------------------------------------------------
extern "C" void kernel_launch(void* const* d_in, const int* in_sizes, int n_in,
                              void* d_out, int out_size, void* d_ws, size_t ws_size,
                              hipStream_t stream)
{
    const float* x      = (const float*)d_in[0];   // [B,H,W,C] = [3200, 384]
    const float* w_qkv  = (const float*)d_in[1];   // [1152, 384]
    const float* w_gp   = (const float*)d_in[2];   // [48, 384] -> (12,48,32)
    const float* w_proj = (const float*)d_in[3];   // [384, 384]
    float* out = (float*)d_out;                    // [B,H,W,C]

    float* ws = (float*)d_ws;
    float* q        = ws;                 // [B,h,N,d] 1228800
    float* kk       = ws + 1228800;
    float* vv       = ws + 2457600;
    float* attn_out = ws + 3686400;       // [B,N,h*d] 1228800
    float* scores   = ws + 4915200;       // [1152][1600] 1843200
    float* qmean    = ws + 6758400;       // [1152][32]   36864
    int*   iws      = (int*)(ws + 6795264);
    int*   gidx     = iws;                // 38400
    int*   topk     = iws + 38400;        // 110592
    int*   qperm    = iws + 38400 + 110592;            // 38400
    int*   qoff     = iws + 38400 + 110592 + 38400;    // 1152
    int*   qcnt     = qoff + 1152;                     // 1152

    // 1) QKV projection, scatter into q/k/v
    gemm_tile<0><<<dim3(QKV_COLS/64, (NB*NN)/64), 256, 0, stream>>>(
        x, w_qkv, q, kk, vv, NB*NN, QKV_COLS, CC);

    // 2) query -> group routing
    group_route<<<NQ/256, 256, 0, stream>>>(q, w_gp, gidx);

    // 3a) deterministic group means + query buckets (1152 blocks)
    qmean_all2<<<BHN*GN, 256, 0, stream>>>(q, gidx, qmean, qperm, qoff, qcnt);

    // 3b) group->key score matrix
    score_all<<<dim3(7, BHN), 256, 0, stream>>>(qmean, kk, scores);

    // 3c) per-wave barrier-free radix top-96
    topk_radix<<<(BHN*GN)/4, 256, 0, stream>>>(scores, topk);

    // 4) group-bucketed sparse attention, split-S load balancing (2304 blocks)
    sparse_attn7<<<BHN*GN*2, 256, 0, stream>>>(q, kk, vv, topk, qperm, qoff, qcnt, attn_out);

    // 5) output projection
    gemm_tile<1><<<dim3(CC/64, (NB*NN)/64), 256, 0, stream>>>(
        attn_out, w_proj, out, nullptr, nullptr, NB*NN, CC, CC);
}

// Round 12
// 280.534 us; speedup vs baseline: 2.0873x; 1.1062x over previous
//
#include <hip/hip_runtime.h>
#include <math.h>

#define NH 12
#define HD 32
#define GN 48
#define TK 96
#define NB 2
#define NN 1600
#define CC 384
#define BHN (NB*NH)          // 24
#define QKV_COLS (3*NH*HD)   // 1152
#define NQ (BHN*NN)          // 38400 total (b,h,n) queries
#define KP 36                // padded K row: bank-quad = 4*((row+chunk)%8)

// ---------------------------------------------------------------------------
// GEMM: out = A[M,K] @ B[N,K]^T   (both row-major; B rows are output cols)
// MODE 0: scatter epilogue into q/k/v [B,h,N,d]   MODE 1: plain store [M,N]
// ---------------------------------------------------------------------------
template<int MODE>
__global__ __launch_bounds__(256)
void gemm_tile(const float* __restrict__ A, const float* __restrict__ B,
               float* __restrict__ o0, float* __restrict__ o1, float* __restrict__ o2,
               int M, int N, int K)
{
    __shared__ float As[16][64];
    __shared__ float Bs[16][64];
    const int tid = threadIdx.x;
    const int tx = tid & 15, ty = tid >> 4;
    const int m0 = blockIdx.y * 64, n0 = blockIdx.x * 64;
    const int lr = tid >> 2;          // tile row 0..63
    const int lc = (tid & 3) * 4;     // k-seg 0,4,8,12
    float acc[4][4] = {};

    for (int k0 = 0; k0 < K; k0 += 16) {
        float4 av = *(const float4*)&A[(m0 + lr) * K + k0 + lc];
        float4 bv = *(const float4*)&B[(n0 + lr) * K + k0 + lc];
        __syncthreads();   // previous iter's compute done before overwrite
        As[lc+0][lr] = av.x; As[lc+1][lr] = av.y; As[lc+2][lr] = av.z; As[lc+3][lr] = av.w;
        Bs[lc+0][lr] = bv.x; Bs[lc+1][lr] = bv.y; Bs[lc+2][lr] = bv.z; Bs[lc+3][lr] = bv.w;
        __syncthreads();
        #pragma unroll
        for (int kk = 0; kk < 16; ++kk) {
            float4 a4 = *(const float4*)&As[kk][ty*4];
            float4 b4 = *(const float4*)&Bs[kk][tx*4];
            float a[4] = {a4.x, a4.y, a4.z, a4.w};
            float b[4] = {b4.x, b4.y, b4.z, b4.w};
            #pragma unroll
            for (int i = 0; i < 4; ++i)
                #pragma unroll
                for (int j = 0; j < 4; ++j)
                    acc[i][j] = fmaf(a[i], b[j], acc[i][j]);
        }
    }

    if (MODE == 0) {
        #pragma unroll
        for (int i = 0; i < 4; ++i) {
            int row = m0 + ty*4 + i;
            int b  = row / NN;
            int nn = row - b * NN;
            #pragma unroll
            for (int j = 0; j < 4; ++j) {
                int col = n0 + tx*4 + j;
                int which = col / CC;          // uniform per tile (384 % 64 == 0)
                int rem = col - which * CC;
                int hh = rem >> 5, dd = rem & 31;
                float* dst = (which == 0) ? o0 : (which == 1) ? o1 : o2;
                dst[((b*NH + hh)*NN + nn)*HD + dd] = acc[i][j];
            }
        }
    } else {
        #pragma unroll
        for (int i = 0; i < 4; ++i) {
            int row = m0 + ty*4 + i;
            float4 st = make_float4(acc[i][0], acc[i][1], acc[i][2], acc[i][3]);
            *(float4*)&o0[row * N + n0 + tx*4] = st;
        }
    }
}

// ---------------------------------------------------------------------------
// Kernel 2: per-query group argmax (gidx), strict > == jnp.argmax tie-break
// ---------------------------------------------------------------------------
__global__ __launch_bounds__(256)
void group_route(const float* __restrict__ q, const float* __restrict__ wgp,
                 int* __restrict__ gidx)
{
    int t = blockIdx.x * 256 + threadIdx.x;   // [0, NQ)
    int bh = t / NN;
    int hh = bh % NH;
    const float* qp = q + t * HD;
    float qr[HD];
    #pragma unroll
    for (int i = 0; i < HD; i += 4) {
        float4 x = *(const float4*)&qp[i];
        qr[i] = x.x; qr[i+1] = x.y; qr[i+2] = x.z; qr[i+3] = x.w;
    }
    float best = -INFINITY; int bg = 0;
    for (int g = 0; g < GN; ++g) {
        const float* gp = wgp + hh*GN*HD + g*HD;
        float s = 0.f;
        #pragma unroll
        for (int i = 0; i < HD; i += 4) {
            float4 w = *(const float4*)&gp[i];
            s += qr[i]*w.x + qr[i+1]*w.y + qr[i+2]*w.z + qr[i+3]*w.w;
        }
        if (s > best) { best = s; bg = g; }
    }
    gidx[t] = bg;
}

// ---------------------------------------------------------------------------
// Kernel 3a (v3): per-(bh,g) deterministic group-mean (register accumulation,
// round-1 summation order) + query bucketing (qperm/qoff/qcnt) for attention.
// 1152 blocks.
// ---------------------------------------------------------------------------
__global__ __launch_bounds__(256)
void qmean_all2(const float* __restrict__ q, const int* __restrict__ gidx,
                float* __restrict__ qmean, int* __restrict__ qperm,
                int* __restrict__ qoff, int* __restrict__ qcnt)
{
    __shared__ float part[8][HD];
    __shared__ int   cnts[8];
    __shared__ int   off_s, pos_s;
    const int bid = blockIdx.x;       // bh*GN + g
    const int g = bid % GN, bh = bid / GN;
    const int tid = threadIdx.x;
    const int s = tid >> 5, dd = tid & 31;

    const int* __restrict__ gx = gidx + bh*NN;
    const float* __restrict__ qb = q + bh*NN*HD;

    if (tid == 0) { off_s = 0; pos_s = 0; }

    float p = 0.f; int c = 0;
    for (int n = s; n < NN; n += 8) {
        if (gx[n] == g) { p += qb[n*HD + dd]; c++; }
    }
    part[s][dd] = p;
    if (dd == 0) cnts[s] = c;
    __syncthreads();                  // part[] + off_s/pos_s init visible

    if (tid < HD) {
        float sum = 0.f; int ct = 0;
        #pragma unroll
        for (int ss = 0; ss < 8; ++ss) { sum += part[ss][tid]; ct += cnts[ss]; }
        qmean[bid*HD + tid] = ct ? sum / (float)ct : 0.f;
    }

    // bucketing: offset = #queries in groups < g (gx row is L1-hot now)
    int mo = 0;
    for (int n = tid; n < NN; n += 256) mo += (gx[n] < g);
    atomicAdd(&off_s, mo);
    __syncthreads();
    for (int n = tid; n < NN; n += 256) {
        if (gx[n] == g) {
            int pp = atomicAdd(&pos_s, 1);
            qperm[bh*NN + off_s + pp] = n;
        }
    }
    __syncthreads();
    if (tid == 0) { qoff[bid] = off_s; qcnt[bid] = pos_s; }
}

// ---------------------------------------------------------------------------
// Kernel 3b: scores[bh*GN+g][n] = qmean[bh,g] . k[bh,n]. Thread owns one n,
// k-row in registers, qmean tile in LDS (broadcast reads), coalesced stores.
// ---------------------------------------------------------------------------
__global__ __launch_bounds__(256)
void score_all(const float* __restrict__ qmean, const float* __restrict__ k,
               float* __restrict__ scores)
{
    __shared__ float Qs[GN][HD];          // 6 KB
    const int bh = blockIdx.y;
    const int tid = threadIdx.x;
    const int n = blockIdx.x*256 + tid;
    for (int i = tid; i < GN*HD; i += 256)
        ((float*)Qs)[i] = qmean[bh*GN*HD + i];
    __syncthreads();
    if (n >= NN) return;
    const float* __restrict__ kp = k + (bh*NN + n)*HD;
    float4 kr[8];
    #pragma unroll
    for (int c = 0; c < 8; ++c) kr[c] = *(const float4*)&kp[c*4];
    for (int g = 0; g < GN; ++g) {
        float s = 0.f;
        #pragma unroll
        for (int c = 0; c < 8; ++c) {
            float4 qv = *(const float4*)&Qs[g][c*4];   // same-addr broadcast
            s += kr[c].x*qv.x + kr[c].y*qv.y + kr[c].z*qv.z + kr[c].w*qv.w;
        }
        scores[(bh*GN + g)*NN + n] = s;               // coalesced per g
    }
}

// ---------------------------------------------------------------------------
// Kernel 3c: per-WAVE barrier-free radix top-96. Each 64-lane wave owns one
// (bh,g) row of 1600 scores: keys + 256-bin hist live in per-wave LDS slices
// (DS ops from a wave complete in program order -> no __syncthreads).
// Suffix-scan in registers via shfl; pivot via ballot; collect via ballot-
// compaction in ascending index order (== lax.top_k lowest-index ties).
// ---------------------------------------------------------------------------
__global__ __launch_bounds__(256)
void topk_radix(const float* __restrict__ scores, int* __restrict__ topk)
{
    __shared__ unsigned keysL[4][NN];     // 25.6 KB
    __shared__ unsigned histL[4][256];    // 4 KB
    const int tid = threadIdx.x;
    const int w = tid >> 6, lane = tid & 63;
    const int gid = blockIdx.x*4 + w;     // (bh*GN + g) in [0,1152)
    const float* __restrict__ row = scores + gid*NN;
    unsigned* keys = keysL[w];
    unsigned* hist = histL[w];

    // load + order-preserving transform (1600 = 25*64 exactly)
    #pragma unroll
    for (int i = 0; i < 25; ++i) {
        int m = lane + 64*i;
        unsigned u = __float_as_uint(row[m]);
        u = (u & 0x80000000u) ? ~u : (u | 0x80000000u);
        keys[m] = u;
    }

    unsigned prefix = 0, r = TK;
    #pragma unroll
    for (int pass = 0; pass < 4; ++pass) {
        const int shift = 24 - 8*pass;
        #pragma unroll
        for (int j = 0; j < 4; ++j) hist[lane*4 + j] = 0;
        #pragma unroll
        for (int i = 0; i < 25; ++i) {
            unsigned u = keys[lane + 64*i];
            bool match = (pass == 0) || ((u >> (shift+8)) == (prefix >> (shift+8)));
            if (match) atomicAdd(&hist[(u >> shift) & 255u], 1u);
        }
        // suffix scan: lane holds bins 4L..4L+3
        uint4 h = *(const uint4*)&hist[lane*4];
        unsigned s3 = h.w, s2 = h.z + s3, s1 = h.y + s2, s0 = h.x + s1;
        unsigned I = s0;                      // inclusive suffix over lane totals
        #pragma unroll
        for (int off = 1; off < 64; off <<= 1) {
            unsigned t = __shfl_down(I, off);
            if (lane + off < 64) I += t;
        }
        unsigned E = I - s0;                  // strict suffix (lanes > L)
        unsigned sf[5] = {E+s0, E+s1, E+s2, E+s3, E};
        int bj = -1; unsigned subc = 0;
        #pragma unroll
        for (int j = 0; j < 4; ++j)
            if (sf[j] >= r && sf[j+1] < r) { bj = j; subc = sf[j+1]; }
        unsigned long long mask = __ballot(bj >= 0);   // exactly one bit set
        int src = __ffsll(mask) - 1;
        int bstar = __shfl(lane*4 + bj, src);
        unsigned sub = (unsigned)__shfl((int)subc, src);
        prefix |= ((unsigned)bstar) << shift;
        r -= sub;
    }
    const unsigned P = prefix;   // exact 96th-largest key; r = #equals to take

    // collect: all keys > P, then first r keys == P (ascending index)
    int* tko = topk + gid*TK;
    int base = 0;
    #pragma unroll
    for (int i = 0; i < 25; ++i) {
        int m = lane + 64*i;
        bool gt = (keys[m] > P);
        unsigned long long mask = __ballot(gt);
        if (gt) tko[base + __popcll(mask & ((1ull << lane) - 1ull))] = m;
        base += (int)__popcll(mask);
    }
    #pragma unroll
    for (int i = 0; i < 25; ++i) {
        int m = lane + 64*i;
        bool eq = (keys[m] == P);
        unsigned long long mask = __ballot(eq);
        if (eq) {
            int pos = base + (int)__popcll(mask & ((1ull << lane) - 1ull));
            if (pos < TK) tko[pos] = m;
        }
        base += (int)__popcll(mask);
    }
}

// ---------------------------------------------------------------------------
// Kernel 4 (v8): v7 minus ALL phase-1 shuffles. Lane dl computes FULL dots
// for its 12 keys (j = t*8+dl), reading padded Ks rows with fixed chunk
// order c=0..7 (static qr[c] indexing -> no scratch arrays). Padding KP=36
// makes bank-quad(Ks[j*KP+c*4]) = 4*((j+c)%8): the 8 dl lanes hit 8 distinct
// quads (all 32 banks), 8 query-groups broadcast -> conflict-free.
// DS ops per lane-query: ~600 -> ~312 (288 bpermutes eliminated).
// ---------------------------------------------------------------------------
__global__ __launch_bounds__(256)
void sparse_attn8(const float* __restrict__ q, const float* __restrict__ k,
                  const float* __restrict__ v, const int* __restrict__ topk,
                  const int* __restrict__ qperm, const int* __restrict__ qoff,
                  const int* __restrict__ qcnt, float* __restrict__ out)
{
    __shared__ float Ks[TK*KP];      // 13.8 KB (padded rows)
    __shared__ float Vs[TK*HD];      // 12 KB
    __shared__ float Ps[32][104];    // 13.3 KB, padded row (104%32==8)

    const int sub = blockIdx.x & 1;       // split-S half
    const int bid = blockIdx.x >> 1;      // bh*GN + g
    const int bh = bid / GN;
    const int nq = qcnt[bid];
    if (nq <= sub*32) return;             // this half has no work (uniform)
    const int off = qoff[bid];
    const int tid = threadIdx.x;

    const int* __restrict__ tk = topk + bid*TK;
    const float* __restrict__ kb = k + bh*NN*HD;
    const float* __restrict__ vb = v + bh*NN*HD;

    // stage K (padded) and V: 8 consecutive lanes fetch one 128B row
    for (int idx = tid; idx < TK*8; idx += 256) {
        int row = idx >> 3, ch = idx & 7;
        int r = tk[row];
        *(float4*)&Ks[row*KP + ch*4] = *(const float4*)&kb[r*HD + ch*4];
        ((float4*)Vs)[idx] = *(const float4*)&vb[r*HD + ch*4];
    }
    __syncthreads();

    const float scale = 0.17677669529663687f;   // 32^-0.5
    const int qs = tid >> 3;            // query slot 0..31 (Ps row owner)
    const int dl = tid & 7;             // lane in 8-lane group
    const int b = bh / NH, hh = bh - b*NH;
    const float* __restrict__ qbase = q + bh*NN*HD;
    const int* __restrict__ qlist = qperm + bh*NN + off;

    for (int it0 = sub*32; it0 < nq; it0 += 64) {
        const int qi = it0 + qs;
        const bool act = (qi < nq);
        const int nn = qlist[act ? qi : nq-1];   // safe clamp; group-uniform

        // full q row (8-lane same-address reads: one cache line per group)
        float4 qr[8];
        #pragma unroll
        for (int c = 0; c < 8; ++c) qr[c] = *(const float4*)&qbase[nn*HD + c*4];

        // phase 1: lane dl fully scores keys t*8+dl -> Ps[qs][j]; no shuffles
        #pragma unroll 2
        for (int t = 0; t < 12; ++t) {
            const int j = t*8 + dl;
            float s0 = 0.f, s1 = 0.f, s2 = 0.f, s3 = 0.f;
            #pragma unroll
            for (int c = 0; c < 8; ++c) {
                float4 w = *(const float4*)&Ks[j*KP + c*4];
                s0 = fmaf(qr[c].x, w.x, s0);
                s1 = fmaf(qr[c].y, w.y, s1);
                s2 = fmaf(qr[c].z, w.z, s2);
                s3 = fmaf(qr[c].w, w.w, s3);
            }
            Ps[qs][j] = ((s0 + s1) + (s2 + s3)) * scale;   // wave-coherent
        }

        // softmax over the 96 scores: re-read own 12 (static offsets)
        float raw[12];
        #pragma unroll
        for (int t = 0; t < 12; ++t) raw[t] = Ps[qs][t*8 + dl];
        float m = -INFINITY;
        #pragma unroll
        for (int t = 0; t < 12; ++t) m = fmaxf(m, raw[t]);
        #pragma unroll
        for (int o = 1; o < 8; o <<= 1) m = fmaxf(m, __shfl_xor(m, o));
        float l = 0.f;
        #pragma unroll
        for (int t = 0; t < 12; ++t) l += __expf(raw[t] - m);
        #pragma unroll
        for (int o = 1; o < 8; o <<= 1) l += __shfl_xor(l, o);
        const float inv = 1.0f / l;
        #pragma unroll
        for (int t = 0; t < 12; ++t) Ps[qs][t*8 + dl] = __expf(raw[t] - m) * inv;

        // phase 2: weighted V sum; p via LDS broadcast (no shuffles)
        float a0 = 0.f, a1 = 0.f, a2 = 0.f, a3 = 0.f;
        #pragma unroll 4
        for (int j = 0; j < TK; ++j) {
            const float p = Ps[qs][j];                       // 8-lane broadcast
            float4 vv = *(const float4*)&Vs[j*HD + dl*4];    // bcast across groups
            a0 = fmaf(p, vv.x, a0);
            a1 = fmaf(p, vv.y, a1);
            a2 = fmaf(p, vv.z, a2);
            a3 = fmaf(p, vv.w, a3);
        }

        if (act) {
            float* op = out + (b*NN + nn)*CC + hh*HD + dl*4;
            *(float4*)op = make_float4(a0, a1, a2, a3);
        }
    }
}

// ---------------------------------------------------------------------------
extern "C" void kernel_launch(void* const* d_in, const int* in_sizes, int n_in,
                              void* d_out, int out_size, void* d_ws, size_t ws_size,
                              hipStream_t stream)
{
    const float* x      = (const float*)d_in[0];   // [B,H,W,C] = [3200, 384]
    const float* w_qkv  = (const float*)d_in[1];   // [1152, 384]
    const float* w_gp   = (const float*)d_in[2];   // [48, 384] -> (12,48,32)
    const float* w_proj = (const float*)d_in[3];   // [384, 384]
    float* out = (float*)d_out;                    // [B,H,W,C]

    float* ws = (float*)d_ws;
    float* q        = ws;                 // [B,h,N,d] 1228800
    float* kk       = ws + 1228800;
    float* vv       = ws + 2457600;
    float* attn_out = ws + 3686400;       // [B,N,h*d] 1228800
    float* scores   = ws + 4915200;       // [1152][1600] 1843200
    float* qmean    = ws + 6758400;       // [1152][32]   36864
    int*   iws      = (int*)(ws + 6795264);
    int*   gidx     = iws;                // 38400
    int*   topk     = iws + 38400;        // 110592
    int*   qperm    = iws + 38400 + 110592;            // 38400
    int*   qoff     = iws + 38400 + 110592 + 38400;    // 1152
    int*   qcnt     = qoff + 1152;                     // 1152

    // 1) QKV projection, scatter into q/k/v
    gemm_tile<0><<<dim3(QKV_COLS/64, (NB*NN)/64), 256, 0, stream>>>(
        x, w_qkv, q, kk, vv, NB*NN, QKV_COLS, CC);

    // 2) query -> group routing
    group_route<<<NQ/256, 256, 0, stream>>>(q, w_gp, gidx);

    // 3a) deterministic group means + query buckets (1152 blocks)
    qmean_all2<<<BHN*GN, 256, 0, stream>>>(q, gidx, qmean, qperm, qoff, qcnt);

    // 3b) group->key score matrix
    score_all<<<dim3(7, BHN), 256, 0, stream>>>(qmean, kk, scores);

    // 3c) per-wave barrier-free radix top-96
    topk_radix<<<(BHN*GN)/4, 256, 0, stream>>>(scores, topk);

    // 4) group-bucketed sparse attention, shuffle-free phase 1 (2304 blocks)
    sparse_attn8<<<BHN*GN*2, 256, 0, stream>>>(q, kk, vv, topk, qperm, qoff, qcnt, attn_out);

    // 5) output projection
    gemm_tile<1><<<dim3(CC/64, (NB*NN)/64), 256, 0, stream>>>(
        attn_out, w_proj, out, nullptr, nullptr, NB*NN, CC, CC);
}

// Round 13
// 249.556 us; speedup vs baseline: 2.3464x; 1.1241x over previous
//
#include <hip/hip_runtime.h>
#include <math.h>

#define NH 12
#define HD 32
#define GN 48
#define TK 96
#define NB 2
#define NN 1600
#define CC 384
#define BHN (NB*NH)          // 24
#define QKV_COLS (3*NH*HD)   // 1152
#define NQ (BHN*NN)          // 38400 total (b,h,n) queries
#define KP 36                // padded K row: bank-quad = 4*((row+chunk)%8)
#define LP 68                // gemm LDS row pad: 68%32=4 -> 2-way writes (free)

// ---------------------------------------------------------------------------
// GEMM: out = A[M,K] @ B[N,K]^T   (both row-major; B rows are output cols)
// MODE 0: scatter epilogue into q/k/v [B,h,N,d]   MODE 1: plain store [M,N]
// LDS rows padded to LP=68 floats: staging writes hit all 32 banks at
// exactly 2 lanes/bank (free); reads stay 16B-aligned (272=17*16), <=2-way.
// ---------------------------------------------------------------------------
template<int MODE>
__global__ __launch_bounds__(256)
void gemm_tile(const float* __restrict__ A, const float* __restrict__ B,
               float* __restrict__ o0, float* __restrict__ o1, float* __restrict__ o2,
               int M, int N, int K)
{
    __shared__ float As[16][LP];
    __shared__ float Bs[16][LP];
    const int tid = threadIdx.x;
    const int tx = tid & 15, ty = tid >> 4;
    const int m0 = blockIdx.y * 64, n0 = blockIdx.x * 64;
    const int lr = tid >> 2;          // tile row 0..63
    const int lc = (tid & 3) * 4;     // k-seg 0,4,8,12
    float acc[4][4] = {};

    for (int k0 = 0; k0 < K; k0 += 16) {
        float4 av = *(const float4*)&A[(m0 + lr) * K + k0 + lc];
        float4 bv = *(const float4*)&B[(n0 + lr) * K + k0 + lc];
        __syncthreads();   // previous iter's compute done before overwrite
        As[lc+0][lr] = av.x; As[lc+1][lr] = av.y; As[lc+2][lr] = av.z; As[lc+3][lr] = av.w;
        Bs[lc+0][lr] = bv.x; Bs[lc+1][lr] = bv.y; Bs[lc+2][lr] = bv.z; Bs[lc+3][lr] = bv.w;
        __syncthreads();
        #pragma unroll
        for (int kk = 0; kk < 16; ++kk) {
            float4 a4 = *(const float4*)&As[kk][ty*4];
            float4 b4 = *(const float4*)&Bs[kk][tx*4];
            float a[4] = {a4.x, a4.y, a4.z, a4.w};
            float b[4] = {b4.x, b4.y, b4.z, b4.w};
            #pragma unroll
            for (int i = 0; i < 4; ++i)
                #pragma unroll
                for (int j = 0; j < 4; ++j)
                    acc[i][j] = fmaf(a[i], b[j], acc[i][j]);
        }
    }

    if (MODE == 0) {
        #pragma unroll
        for (int i = 0; i < 4; ++i) {
            int row = m0 + ty*4 + i;
            int b  = row / NN;
            int nn = row - b * NN;
            #pragma unroll
            for (int j = 0; j < 4; ++j) {
                int col = n0 + tx*4 + j;
                int which = col / CC;          // uniform per tile (384 % 64 == 0)
                int rem = col - which * CC;
                int hh = rem >> 5, dd = rem & 31;
                float* dst = (which == 0) ? o0 : (which == 1) ? o1 : o2;
                dst[((b*NH + hh)*NN + nn)*HD + dd] = acc[i][j];
            }
        }
    } else {
        #pragma unroll
        for (int i = 0; i < 4; ++i) {
            int row = m0 + ty*4 + i;
            float4 st = make_float4(acc[i][0], acc[i][1], acc[i][2], acc[i][3]);
            *(float4*)&o0[row * N + n0 + tx*4] = st;
        }
    }
}

// ---------------------------------------------------------------------------
// Kernel 2: per-query group argmax (gidx), strict > == jnp.argmax tie-break
// ---------------------------------------------------------------------------
__global__ __launch_bounds__(256)
void group_route(const float* __restrict__ q, const float* __restrict__ wgp,
                 int* __restrict__ gidx)
{
    int t = blockIdx.x * 256 + threadIdx.x;   // [0, NQ)
    int bh = t / NN;
    int hh = bh % NH;
    const float* qp = q + t * HD;
    float qr[HD];
    #pragma unroll
    for (int i = 0; i < HD; i += 4) {
        float4 x = *(const float4*)&qp[i];
        qr[i] = x.x; qr[i+1] = x.y; qr[i+2] = x.z; qr[i+3] = x.w;
    }
    float best = -INFINITY; int bg = 0;
    for (int g = 0; g < GN; ++g) {
        const float* gp = wgp + hh*GN*HD + g*HD;
        float s = 0.f;
        #pragma unroll
        for (int i = 0; i < HD; i += 4) {
            float4 w = *(const float4*)&gp[i];
            s += qr[i]*w.x + qr[i+1]*w.y + qr[i+2]*w.z + qr[i+3]*w.w;
        }
        if (s > best) { best = s; bg = g; }
    }
    gidx[t] = bg;
}

// ---------------------------------------------------------------------------
// Kernel 3a (v4): per-(bh,g) deterministic group-mean, BRANCHLESS always-load
// (round-12 lesson: conditional loads built a VGPR-8 serial latency chain).
// Slice s=tid>>5 scans contiguous rows [s*200,(s+1)*200); gx read as int4;
// q loads unconditional (static addresses -> pipelined), mask applied after.
// Fixed order -> deterministic. + query bucketing (qperm/qoff/qcnt).
// ---------------------------------------------------------------------------
__global__ __launch_bounds__(256)
void qmean_all2(const float* __restrict__ q, const int* __restrict__ gidx,
                float* __restrict__ qmean, int* __restrict__ qperm,
                int* __restrict__ qoff, int* __restrict__ qcnt)
{
    __shared__ float part[8][HD];
    __shared__ int   cnts[8];
    __shared__ int   off_s, pos_s;
    const int bid = blockIdx.x;       // bh*GN + g
    const int g = bid % GN, bh = bid / GN;
    const int tid = threadIdx.x;
    const int s = tid >> 5, dd = tid & 31;

    const int* __restrict__ gx = gidx + bh*NN;
    const float* __restrict__ qb = q + bh*NN*HD;

    if (tid == 0) { off_s = 0; pos_s = 0; }

    const int base = s * 200;         // 1600/8 rows per slice, contiguous
    float p = 0.f; int c = 0;
    #pragma unroll 2
    for (int n0 = 0; n0 < 200; n0 += 4) {
        int4 g4 = *(const int4*)&gx[base + n0];
        float v0 = qb[(base+n0+0)*HD + dd];   // unconditional: pipelines
        float v1 = qb[(base+n0+1)*HD + dd];
        float v2 = qb[(base+n0+2)*HD + dd];
        float v3 = qb[(base+n0+3)*HD + dd];
        if (g4.x == g) { p += v0; c++; }      // cndmask+add, no branch
        if (g4.y == g) { p += v1; c++; }
        if (g4.z == g) { p += v2; c++; }
        if (g4.w == g) { p += v3; c++; }
    }
    part[s][dd] = p;
    if (dd == 0) cnts[s] = c;
    __syncthreads();                  // part[] + off_s/pos_s init visible

    if (tid < HD) {
        float sum = 0.f; int ct = 0;
        #pragma unroll
        for (int ss = 0; ss < 8; ++ss) { sum += part[ss][tid]; ct += cnts[ss]; }
        qmean[bid*HD + tid] = ct ? sum / (float)ct : 0.f;
    }

    // bucketing: offset = #queries in groups < g (gx row is L1-hot now)
    int mo = 0;
    for (int n = tid; n < NN; n += 256) mo += (gx[n] < g);
    atomicAdd(&off_s, mo);
    __syncthreads();
    for (int n = tid; n < NN; n += 256) {
        if (gx[n] == g) {
            int pp = atomicAdd(&pos_s, 1);
            qperm[bh*NN + off_s + pp] = n;
        }
    }
    __syncthreads();
    if (tid == 0) { qoff[bid] = off_s; qcnt[bid] = pos_s; }
}

// ---------------------------------------------------------------------------
// Kernel 3b: scores[bh*GN+g][n] = qmean[bh,g] . k[bh,n]. Thread owns one n,
// k-row in registers, qmean tile in LDS (broadcast reads), coalesced stores.
// ---------------------------------------------------------------------------
__global__ __launch_bounds__(256)
void score_all(const float* __restrict__ qmean, const float* __restrict__ k,
               float* __restrict__ scores)
{
    __shared__ float Qs[GN][HD];          // 6 KB
    const int bh = blockIdx.y;
    const int tid = threadIdx.x;
    const int n = blockIdx.x*256 + tid;
    for (int i = tid; i < GN*HD; i += 256)
        ((float*)Qs)[i] = qmean[bh*GN*HD + i];
    __syncthreads();
    if (n >= NN) return;
    const float* __restrict__ kp = k + (bh*NN + n)*HD;
    float4 kr[8];
    #pragma unroll
    for (int c = 0; c < 8; ++c) kr[c] = *(const float4*)&kp[c*4];
    for (int g = 0; g < GN; ++g) {
        float s = 0.f;
        #pragma unroll
        for (int c = 0; c < 8; ++c) {
            float4 qv = *(const float4*)&Qs[g][c*4];   // same-addr broadcast
            s += kr[c].x*qv.x + kr[c].y*qv.y + kr[c].z*qv.z + kr[c].w*qv.w;
        }
        scores[(bh*GN + g)*NN + n] = s;               // coalesced per g
    }
}

// ---------------------------------------------------------------------------
// Kernel 3c: per-WAVE barrier-free radix top-96. Each 64-lane wave owns one
// (bh,g) row of 1600 scores: keys + 256-bin hist live in per-wave LDS slices
// (DS ops from a wave complete in program order -> no __syncthreads).
// Suffix-scan in registers via shfl; pivot via ballot; collect via ballot-
// compaction in ascending index order (== lax.top_k lowest-index ties).
// ---------------------------------------------------------------------------
__global__ __launch_bounds__(256)
void topk_radix(const float* __restrict__ scores, int* __restrict__ topk)
{
    __shared__ unsigned keysL[4][NN];     // 25.6 KB
    __shared__ unsigned histL[4][256];    // 4 KB
    const int tid = threadIdx.x;
    const int w = tid >> 6, lane = tid & 63;
    const int gid = blockIdx.x*4 + w;     // (bh*GN + g) in [0,1152)
    const float* __restrict__ row = scores + gid*NN;
    unsigned* keys = keysL[w];
    unsigned* hist = histL[w];

    // load + order-preserving transform (1600 = 25*64 exactly)
    #pragma unroll
    for (int i = 0; i < 25; ++i) {
        int m = lane + 64*i;
        unsigned u = __float_as_uint(row[m]);
        u = (u & 0x80000000u) ? ~u : (u | 0x80000000u);
        keys[m] = u;
    }

    unsigned prefix = 0, r = TK;
    #pragma unroll
    for (int pass = 0; pass < 4; ++pass) {
        const int shift = 24 - 8*pass;
        #pragma unroll
        for (int j = 0; j < 4; ++j) hist[lane*4 + j] = 0;
        #pragma unroll
        for (int i = 0; i < 25; ++i) {
            unsigned u = keys[lane + 64*i];
            bool match = (pass == 0) || ((u >> (shift+8)) == (prefix >> (shift+8)));
            if (match) atomicAdd(&hist[(u >> shift) & 255u], 1u);
        }
        // suffix scan: lane holds bins 4L..4L+3
        uint4 h = *(const uint4*)&hist[lane*4];
        unsigned s3 = h.w, s2 = h.z + s3, s1 = h.y + s2, s0 = h.x + s1;
        unsigned I = s0;                      // inclusive suffix over lane totals
        #pragma unroll
        for (int off = 1; off < 64; off <<= 1) {
            unsigned t = __shfl_down(I, off);
            if (lane + off < 64) I += t;
        }
        unsigned E = I - s0;                  // strict suffix (lanes > L)
        unsigned sf[5] = {E+s0, E+s1, E+s2, E+s3, E};
        int bj = -1; unsigned subc = 0;
        #pragma unroll
        for (int j = 0; j < 4; ++j)
            if (sf[j] >= r && sf[j+1] < r) { bj = j; subc = sf[j+1]; }
        unsigned long long mask = __ballot(bj >= 0);   // exactly one bit set
        int src = __ffsll(mask) - 1;
        int bstar = __shfl(lane*4 + bj, src);
        unsigned sub = (unsigned)__shfl((int)subc, src);
        prefix |= ((unsigned)bstar) << shift;
        r -= sub;
    }
    const unsigned P = prefix;   // exact 96th-largest key; r = #equals to take

    // collect: all keys > P, then first r keys == P (ascending index)
    int* tko = topk + gid*TK;
    int base = 0;
    #pragma unroll
    for (int i = 0; i < 25; ++i) {
        int m = lane + 64*i;
        bool gt = (keys[m] > P);
        unsigned long long mask = __ballot(gt);
        if (gt) tko[base + __popcll(mask & ((1ull << lane) - 1ull))] = m;
        base += (int)__popcll(mask);
    }
    #pragma unroll
    for (int i = 0; i < 25; ++i) {
        int m = lane + 64*i;
        bool eq = (keys[m] == P);
        unsigned long long mask = __ballot(eq);
        if (eq) {
            int pos = base + (int)__popcll(mask & ((1ull << lane) - 1ull));
            if (pos < TK) tko[pos] = m;
        }
        base += (int)__popcll(mask);
    }
}

// ---------------------------------------------------------------------------
// Kernel 4 (v8): group-bucketed attention, shuffle-free phase 1 (padded Ks),
// LDS score buffer Ps, split-S. Verified round 12: dropped out of top-5.
// ---------------------------------------------------------------------------
__global__ __launch_bounds__(256)
void sparse_attn8(const float* __restrict__ q, const float* __restrict__ k,
                  const float* __restrict__ v, const int* __restrict__ topk,
                  const int* __restrict__ qperm, const int* __restrict__ qoff,
                  const int* __restrict__ qcnt, float* __restrict__ out)
{
    __shared__ float Ks[TK*KP];      // 13.8 KB (padded rows)
    __shared__ float Vs[TK*HD];      // 12 KB
    __shared__ float Ps[32][104];    // 13.3 KB, padded row (104%32==8)

    const int sub = blockIdx.x & 1;       // split-S half
    const int bid = blockIdx.x >> 1;      // bh*GN + g
    const int bh = bid / GN;
    const int nq = qcnt[bid];
    if (nq <= sub*32) return;             // this half has no work (uniform)
    const int off = qoff[bid];
    const int tid = threadIdx.x;

    const int* __restrict__ tk = topk + bid*TK;
    const float* __restrict__ kb = k + bh*NN*HD;
    const float* __restrict__ vb = v + bh*NN*HD;

    // stage K (padded) and V: 8 consecutive lanes fetch one 128B row
    for (int idx = tid; idx < TK*8; idx += 256) {
        int row = idx >> 3, ch = idx & 7;
        int r = tk[row];
        *(float4*)&Ks[row*KP + ch*4] = *(const float4*)&kb[r*HD + ch*4];
        ((float4*)Vs)[idx] = *(const float4*)&vb[r*HD + ch*4];
    }
    __syncthreads();

    const float scale = 0.17677669529663687f;   // 32^-0.5
    const int qs = tid >> 3;            // query slot 0..31 (Ps row owner)
    const int dl = tid & 7;             // lane in 8-lane group
    const int b = bh / NH, hh = bh - b*NH;
    const float* __restrict__ qbase = q + bh*NN*HD;
    const int* __restrict__ qlist = qperm + bh*NN + off;

    for (int it0 = sub*32; it0 < nq; it0 += 64) {
        const int qi = it0 + qs;
        const bool act = (qi < nq);
        const int nn = qlist[act ? qi : nq-1];   // safe clamp; group-uniform

        // full q row (8-lane same-address reads: one cache line per group)
        float4 qr[8];
        #pragma unroll
        for (int c = 0; c < 8; ++c) qr[c] = *(const float4*)&qbase[nn*HD + c*4];

        // phase 1: lane dl fully scores keys t*8+dl -> Ps[qs][j]; no shuffles
        #pragma unroll 2
        for (int t = 0; t < 12; ++t) {
            const int j = t*8 + dl;
            float s0 = 0.f, s1 = 0.f, s2 = 0.f, s3 = 0.f;
            #pragma unroll
            for (int c = 0; c < 8; ++c) {
                float4 w = *(const float4*)&Ks[j*KP + c*4];
                s0 = fmaf(qr[c].x, w.x, s0);
                s1 = fmaf(qr[c].y, w.y, s1);
                s2 = fmaf(qr[c].z, w.z, s2);
                s3 = fmaf(qr[c].w, w.w, s3);
            }
            Ps[qs][j] = ((s0 + s1) + (s2 + s3)) * scale;   // wave-coherent
        }

        // softmax over the 96 scores: re-read own 12 (static offsets)
        float raw[12];
        #pragma unroll
        for (int t = 0; t < 12; ++t) raw[t] = Ps[qs][t*8 + dl];
        float m = -INFINITY;
        #pragma unroll
        for (int t = 0; t < 12; ++t) m = fmaxf(m, raw[t]);
        #pragma unroll
        for (int o = 1; o < 8; o <<= 1) m = fmaxf(m, __shfl_xor(m, o));
        float l = 0.f;
        #pragma unroll
        for (int t = 0; t < 12; ++t) l += __expf(raw[t] - m);
        #pragma unroll
        for (int o = 1; o < 8; o <<= 1) l += __shfl_xor(l, o);
        const float inv = 1.0f / l;
        #pragma unroll
        for (int t = 0; t < 12; ++t) Ps[qs][t*8 + dl] = __expf(raw[t] - m) * inv;

        // phase 2: weighted V sum; p via LDS broadcast (no shuffles)
        float a0 = 0.f, a1 = 0.f, a2 = 0.f, a3 = 0.f;
        #pragma unroll 4
        for (int j = 0; j < TK; ++j) {
            const float p = Ps[qs][j];                       // 8-lane broadcast
            float4 vv = *(const float4*)&Vs[j*HD + dl*4];    // bcast across groups
            a0 = fmaf(p, vv.x, a0);
            a1 = fmaf(p, vv.y, a1);
            a2 = fmaf(p, vv.z, a2);
            a3 = fmaf(p, vv.w, a3);
        }

        if (act) {
            float* op = out + (b*NN + nn)*CC + hh*HD + dl*4;
            *(float4*)op = make_float4(a0, a1, a2, a3);
        }
    }
}

// ---------------------------------------------------------------------------
extern "C" void kernel_launch(void* const* d_in, const int* in_sizes, int n_in,
                              void* d_out, int out_size, void* d_ws, size_t ws_size,
                              hipStream_t stream)
{
    const float* x      = (const float*)d_in[0];   // [B,H,W,C] = [3200, 384]
    const float* w_qkv  = (const float*)d_in[1];   // [1152, 384]
    const float* w_gp   = (const float*)d_in[2];   // [48, 384] -> (12,48,32)
    const float* w_proj = (const float*)d_in[3];   // [384, 384]
    float* out = (float*)d_out;                    // [B,H,W,C]

    float* ws = (float*)d_ws;
    float* q        = ws;                 // [B,h,N,d] 1228800
    float* kk       = ws + 1228800;
    float* vv       = ws + 2457600;
    float* attn_out = ws + 3686400;       // [B,N,h*d] 1228800
    float* scores   = ws + 4915200;       // [1152][1600] 1843200
    float* qmean    = ws + 6758400;       // [1152][32]   36864
    int*   iws      = (int*)(ws + 6795264);
    int*   gidx     = iws;                // 38400
    int*   topk     = iws + 38400;        // 110592
    int*   qperm    = iws + 38400 + 110592;            // 38400
    int*   qoff     = iws + 38400 + 110592 + 38400;    // 1152
    int*   qcnt     = qoff + 1152;                     // 1152

    // 1) QKV projection, scatter into q/k/v
    gemm_tile<0><<<dim3(QKV_COLS/64, (NB*NN)/64), 256, 0, stream>>>(
        x, w_qkv, q, kk, vv, NB*NN, QKV_COLS, CC);

    // 2) query -> group routing
    group_route<<<NQ/256, 256, 0, stream>>>(q, w_gp, gidx);

    // 3a) deterministic group means (branchless) + query buckets
    qmean_all2<<<BHN*GN, 256, 0, stream>>>(q, gidx, qmean, qperm, qoff, qcnt);

    // 3b) group->key score matrix
    score_all<<<dim3(7, BHN), 256, 0, stream>>>(qmean, kk, scores);

    // 3c) per-wave barrier-free radix top-96
    topk_radix<<<(BHN*GN)/4, 256, 0, stream>>>(scores, topk);

    // 4) group-bucketed sparse attention, shuffle-free phase 1 (2304 blocks)
    sparse_attn8<<<BHN*GN*2, 256, 0, stream>>>(q, kk, vv, topk, qperm, qoff, qcnt, attn_out);

    // 5) output projection
    gemm_tile<1><<<dim3(CC/64, (NB*NN)/64), 256, 0, stream>>>(
        attn_out, w_proj, out, nullptr, nullptr, NB*NN, CC, CC);
}

// Round 14
// 245.229 us; speedup vs baseline: 2.3878x; 1.0176x over previous
//
#include <hip/hip_runtime.h>
#include <math.h>

#define NH 12
#define HD 32
#define GN 48
#define TK 96
#define NB 2
#define NN 1600
#define CC 384
#define BHN (NB*NH)          // 24
#define QKV_COLS (3*NH*HD)   // 1152
#define NQ (BHN*NN)          // 38400 total (b,h,n) queries
#define KP 36                // padded K row: bank-quad = 4*((row+chunk)%8)
#define LP 68                // gemm LDS row pad: 68%32=4 -> 2-way writes (free)

// ---------------------------------------------------------------------------
// GEMM: out = A[M,K] @ B[N,K]^T   (both row-major; B rows are output cols)
// MODE 0: scatter epilogue into q/k/v [B,h,N,d]   MODE 1: plain store [M,N]
// Round-14 structure: double-buffered LDS (ONE barrier per K-iter) +
// register prefetch issued BEFORE the compute block, so the vmcnt drain at
// ds_write / s_barrier finds data already arrived (round-13: 59% stall).
// Accumulation order unchanged -> bitwise-identical results.
// ---------------------------------------------------------------------------
template<int MODE>
__global__ __launch_bounds__(256)
void gemm_tile(const float* __restrict__ A, const float* __restrict__ B,
               float* __restrict__ o0, float* __restrict__ o1, float* __restrict__ o2,
               int M, int N, int K)
{
    __shared__ float As[2][16][LP];
    __shared__ float Bs[2][16][LP];
    const int tid = threadIdx.x;
    const int tx = tid & 15, ty = tid >> 4;
    const int m0 = blockIdx.y * 64, n0 = blockIdx.x * 64;
    const int lr = tid >> 2;          // tile row 0..63
    const int lc = (tid & 3) * 4;     // k-seg 0,4,8,12
    const float* __restrict__ Ap = &A[(m0 + lr) * K + lc];
    const float* __restrict__ Bp = &B[(n0 + lr) * K + lc];
    float acc[4][4] = {};

    // stage tile 0 into buffer 0
    {
        float4 av = *(const float4*)Ap;
        float4 bv = *(const float4*)Bp;
        As[0][lc+0][lr] = av.x; As[0][lc+1][lr] = av.y; As[0][lc+2][lr] = av.z; As[0][lc+3][lr] = av.w;
        Bs[0][lc+0][lr] = bv.x; Bs[0][lc+1][lr] = bv.y; Bs[0][lc+2][lr] = bv.z; Bs[0][lc+3][lr] = bv.w;
    }
    __syncthreads();

    int p = 0;
    for (int k0 = 16; k0 <= K; k0 += 16) {
        // 1) issue next-tile loads FIRST (hidden under the compute below)
        float4 av_n, bv_n;
        const bool more = (k0 < K);
        if (more) {
            av_n = *(const float4*)(Ap + k0);
            bv_n = *(const float4*)(Bp + k0);
        }
        // 2) compute current buffer (~512 VALU cycles)
        #pragma unroll
        for (int kk = 0; kk < 16; ++kk) {
            float4 a4 = *(const float4*)&As[p][kk][ty*4];
            float4 b4 = *(const float4*)&Bs[p][kk][tx*4];
            float a[4] = {a4.x, a4.y, a4.z, a4.w};
            float b[4] = {b4.x, b4.y, b4.z, b4.w};
            #pragma unroll
            for (int i = 0; i < 4; ++i)
                #pragma unroll
                for (int j = 0; j < 4; ++j)
                    acc[i][j] = fmaf(a[i], b[j], acc[i][j]);
        }
        // 3) write next tile to the other buffer; 4) one barrier
        if (more) {
            As[1-p][lc+0][lr] = av_n.x; As[1-p][lc+1][lr] = av_n.y;
            As[1-p][lc+2][lr] = av_n.z; As[1-p][lc+3][lr] = av_n.w;
            Bs[1-p][lc+0][lr] = bv_n.x; Bs[1-p][lc+1][lr] = bv_n.y;
            Bs[1-p][lc+2][lr] = bv_n.z; Bs[1-p][lc+3][lr] = bv_n.w;
            __syncthreads();
            p ^= 1;
        }
    }

    if (MODE == 0) {
        #pragma unroll
        for (int i = 0; i < 4; ++i) {
            int row = m0 + ty*4 + i;
            int b  = row / NN;
            int nn = row - b * NN;
            #pragma unroll
            for (int j = 0; j < 4; ++j) {
                int col = n0 + tx*4 + j;
                int which = col / CC;          // uniform per tile (384 % 64 == 0)
                int rem = col - which * CC;
                int hh = rem >> 5, dd = rem & 31;
                float* dst = (which == 0) ? o0 : (which == 1) ? o1 : o2;
                dst[((b*NH + hh)*NN + nn)*HD + dd] = acc[i][j];
            }
        }
    } else {
        #pragma unroll
        for (int i = 0; i < 4; ++i) {
            int row = m0 + ty*4 + i;
            float4 st = make_float4(acc[i][0], acc[i][1], acc[i][2], acc[i][3]);
            *(float4*)&o0[row * N + n0 + tx*4] = st;
        }
    }
}

// ---------------------------------------------------------------------------
// Kernel 2: per-query group argmax (gidx), strict > == jnp.argmax tie-break
// ---------------------------------------------------------------------------
__global__ __launch_bounds__(256)
void group_route(const float* __restrict__ q, const float* __restrict__ wgp,
                 int* __restrict__ gidx)
{
    int t = blockIdx.x * 256 + threadIdx.x;   // [0, NQ)
    int bh = t / NN;
    int hh = bh % NH;
    const float* qp = q + t * HD;
    float qr[HD];
    #pragma unroll
    for (int i = 0; i < HD; i += 4) {
        float4 x = *(const float4*)&qp[i];
        qr[i] = x.x; qr[i+1] = x.y; qr[i+2] = x.z; qr[i+3] = x.w;
    }
    float best = -INFINITY; int bg = 0;
    for (int g = 0; g < GN; ++g) {
        const float* gp = wgp + hh*GN*HD + g*HD;
        float s = 0.f;
        #pragma unroll
        for (int i = 0; i < HD; i += 4) {
            float4 w = *(const float4*)&gp[i];
            s += qr[i]*w.x + qr[i+1]*w.y + qr[i+2]*w.z + qr[i+3]*w.w;
        }
        if (s > best) { best = s; bg = g; }
    }
    gidx[t] = bg;
}

// ---------------------------------------------------------------------------
// Kernel 3a (v4): per-(bh,g) deterministic group-mean, branchless always-load
// + query bucketing (qperm/qoff/qcnt). 1152 blocks.
// ---------------------------------------------------------------------------
__global__ __launch_bounds__(256)
void qmean_all2(const float* __restrict__ q, const int* __restrict__ gidx,
                float* __restrict__ qmean, int* __restrict__ qperm,
                int* __restrict__ qoff, int* __restrict__ qcnt)
{
    __shared__ float part[8][HD];
    __shared__ int   cnts[8];
    __shared__ int   off_s, pos_s;
    const int bid = blockIdx.x;       // bh*GN + g
    const int g = bid % GN, bh = bid / GN;
    const int tid = threadIdx.x;
    const int s = tid >> 5, dd = tid & 31;

    const int* __restrict__ gx = gidx + bh*NN;
    const float* __restrict__ qb = q + bh*NN*HD;

    if (tid == 0) { off_s = 0; pos_s = 0; }

    const int base = s * 200;         // 1600/8 rows per slice, contiguous
    float p = 0.f; int c = 0;
    #pragma unroll 2
    for (int n0 = 0; n0 < 200; n0 += 4) {
        int4 g4 = *(const int4*)&gx[base + n0];
        float v0 = qb[(base+n0+0)*HD + dd];   // unconditional: pipelines
        float v1 = qb[(base+n0+1)*HD + dd];
        float v2 = qb[(base+n0+2)*HD + dd];
        float v3 = qb[(base+n0+3)*HD + dd];
        if (g4.x == g) { p += v0; c++; }      // cndmask+add, no branch
        if (g4.y == g) { p += v1; c++; }
        if (g4.z == g) { p += v2; c++; }
        if (g4.w == g) { p += v3; c++; }
    }
    part[s][dd] = p;
    if (dd == 0) cnts[s] = c;
    __syncthreads();                  // part[] + off_s/pos_s init visible

    if (tid < HD) {
        float sum = 0.f; int ct = 0;
        #pragma unroll
        for (int ss = 0; ss < 8; ++ss) { sum += part[ss][tid]; ct += cnts[ss]; }
        qmean[bid*HD + tid] = ct ? sum / (float)ct : 0.f;
    }

    // bucketing: offset = #queries in groups < g (gx row is L1-hot now)
    int mo = 0;
    for (int n = tid; n < NN; n += 256) mo += (gx[n] < g);
    atomicAdd(&off_s, mo);
    __syncthreads();
    for (int n = tid; n < NN; n += 256) {
        if (gx[n] == g) {
            int pp = atomicAdd(&pos_s, 1);
            qperm[bh*NN + off_s + pp] = n;
        }
    }
    __syncthreads();
    if (tid == 0) { qoff[bid] = off_s; qcnt[bid] = pos_s; }
}

// ---------------------------------------------------------------------------
// Kernel 3b: scores[bh*GN+g][n] = qmean[bh,g] . k[bh,n]. Thread owns one n,
// k-row in registers, qmean tile in LDS (broadcast reads), coalesced stores.
// ---------------------------------------------------------------------------
__global__ __launch_bounds__(256)
void score_all(const float* __restrict__ qmean, const float* __restrict__ k,
               float* __restrict__ scores)
{
    __shared__ float Qs[GN][HD];          // 6 KB
    const int bh = blockIdx.y;
    const int tid = threadIdx.x;
    const int n = blockIdx.x*256 + tid;
    for (int i = tid; i < GN*HD; i += 256)
        ((float*)Qs)[i] = qmean[bh*GN*HD + i];
    __syncthreads();
    if (n >= NN) return;
    const float* __restrict__ kp = k + (bh*NN + n)*HD;
    float4 kr[8];
    #pragma unroll
    for (int c = 0; c < 8; ++c) kr[c] = *(const float4*)&kp[c*4];
    for (int g = 0; g < GN; ++g) {
        float s = 0.f;
        #pragma unroll
        for (int c = 0; c < 8; ++c) {
            float4 qv = *(const float4*)&Qs[g][c*4];   // same-addr broadcast
            s += kr[c].x*qv.x + kr[c].y*qv.y + kr[c].z*qv.z + kr[c].w*qv.w;
        }
        scores[(bh*GN + g)*NN + n] = s;               // coalesced per g
    }
}

// ---------------------------------------------------------------------------
// Kernel 3c: per-WAVE barrier-free radix top-96. Each 64-lane wave owns one
// (bh,g) row of 1600 scores: keys + 256-bin hist live in per-wave LDS slices
// (DS ops from a wave complete in program order -> no __syncthreads).
// Suffix-scan in registers via shfl; pivot via ballot; collect via ballot-
// compaction in ascending index order (== lax.top_k lowest-index ties).
// ---------------------------------------------------------------------------
__global__ __launch_bounds__(256)
void topk_radix(const float* __restrict__ scores, int* __restrict__ topk)
{
    __shared__ unsigned keysL[4][NN];     // 25.6 KB
    __shared__ unsigned histL[4][256];    // 4 KB
    const int tid = threadIdx.x;
    const int w = tid >> 6, lane = tid & 63;
    const int gid = blockIdx.x*4 + w;     // (bh*GN + g) in [0,1152)
    const float* __restrict__ row = scores + gid*NN;
    unsigned* keys = keysL[w];
    unsigned* hist = histL[w];

    // load + order-preserving transform (1600 = 25*64 exactly)
    #pragma unroll
    for (int i = 0; i < 25; ++i) {
        int m = lane + 64*i;
        unsigned u = __float_as_uint(row[m]);
        u = (u & 0x80000000u) ? ~u : (u | 0x80000000u);
        keys[m] = u;
    }

    unsigned prefix = 0, r = TK;
    #pragma unroll
    for (int pass = 0; pass < 4; ++pass) {
        const int shift = 24 - 8*pass;
        #pragma unroll
        for (int j = 0; j < 4; ++j) hist[lane*4 + j] = 0;
        #pragma unroll
        for (int i = 0; i < 25; ++i) {
            unsigned u = keys[lane + 64*i];
            bool match = (pass == 0) || ((u >> (shift+8)) == (prefix >> (shift+8)));
            if (match) atomicAdd(&hist[(u >> shift) & 255u], 1u);
        }
        // suffix scan: lane holds bins 4L..4L+3
        uint4 h = *(const uint4*)&hist[lane*4];
        unsigned s3 = h.w, s2 = h.z + s3, s1 = h.y + s2, s0 = h.x + s1;
        unsigned I = s0;                      // inclusive suffix over lane totals
        #pragma unroll
        for (int off = 1; off < 64; off <<= 1) {
            unsigned t = __shfl_down(I, off);
            if (lane + off < 64) I += t;
        }
        unsigned E = I - s0;                  // strict suffix (lanes > L)
        unsigned sf[5] = {E+s0, E+s1, E+s2, E+s3, E};
        int bj = -1; unsigned subc = 0;
        #pragma unroll
        for (int j = 0; j < 4; ++j)
            if (sf[j] >= r && sf[j+1] < r) { bj = j; subc = sf[j+1]; }
        unsigned long long mask = __ballot(bj >= 0);   // exactly one bit set
        int src = __ffsll(mask) - 1;
        int bstar = __shfl(lane*4 + bj, src);
        unsigned sub = (unsigned)__shfl((int)subc, src);
        prefix |= ((unsigned)bstar) << shift;
        r -= sub;
    }
    const unsigned P = prefix;   // exact 96th-largest key; r = #equals to take

    // collect: all keys > P, then first r keys == P (ascending index)
    int* tko = topk + gid*TK;
    int base = 0;
    #pragma unroll
    for (int i = 0; i < 25; ++i) {
        int m = lane + 64*i;
        bool gt = (keys[m] > P);
        unsigned long long mask = __ballot(gt);
        if (gt) tko[base + __popcll(mask & ((1ull << lane) - 1ull))] = m;
        base += (int)__popcll(mask);
    }
    #pragma unroll
    for (int i = 0; i < 25; ++i) {
        int m = lane + 64*i;
        bool eq = (keys[m] == P);
        unsigned long long mask = __ballot(eq);
        if (eq) {
            int pos = base + (int)__popcll(mask & ((1ull << lane) - 1ull));
            if (pos < TK) tko[pos] = m;
        }
        base += (int)__popcll(mask);
    }
}

// ---------------------------------------------------------------------------
// Kernel 4 (v8): group-bucketed attention, shuffle-free phase 1 (padded Ks),
// LDS score buffer Ps, split-S. Verified round 12: dropped out of top-5.
// ---------------------------------------------------------------------------
__global__ __launch_bounds__(256)
void sparse_attn8(const float* __restrict__ q, const float* __restrict__ k,
                  const float* __restrict__ v, const int* __restrict__ topk,
                  const int* __restrict__ qperm, const int* __restrict__ qoff,
                  const int* __restrict__ qcnt, float* __restrict__ out)
{
    __shared__ float Ks[TK*KP];      // 13.8 KB (padded rows)
    __shared__ float Vs[TK*HD];      // 12 KB
    __shared__ float Ps[32][104];    // 13.3 KB, padded row (104%32==8)

    const int sub = blockIdx.x & 1;       // split-S half
    const int bid = blockIdx.x >> 1;      // bh*GN + g
    const int bh = bid / GN;
    const int nq = qcnt[bid];
    if (nq <= sub*32) return;             // this half has no work (uniform)
    const int off = qoff[bid];
    const int tid = threadIdx.x;

    const int* __restrict__ tk = topk + bid*TK;
    const float* __restrict__ kb = k + bh*NN*HD;
    const float* __restrict__ vb = v + bh*NN*HD;

    // stage K (padded) and V: 8 consecutive lanes fetch one 128B row
    for (int idx = tid; idx < TK*8; idx += 256) {
        int row = idx >> 3, ch = idx & 7;
        int r = tk[row];
        *(float4*)&Ks[row*KP + ch*4] = *(const float4*)&kb[r*HD + ch*4];
        ((float4*)Vs)[idx] = *(const float4*)&vb[r*HD + ch*4];
    }
    __syncthreads();

    const float scale = 0.17677669529663687f;   // 32^-0.5
    const int qs = tid >> 3;            // query slot 0..31 (Ps row owner)
    const int dl = tid & 7;             // lane in 8-lane group
    const int b = bh / NH, hh = bh - b*NH;
    const float* __restrict__ qbase = q + bh*NN*HD;
    const int* __restrict__ qlist = qperm + bh*NN + off;

    for (int it0 = sub*32; it0 < nq; it0 += 64) {
        const int qi = it0 + qs;
        const bool act = (qi < nq);
        const int nn = qlist[act ? qi : nq-1];   // safe clamp; group-uniform

        // full q row (8-lane same-address reads: one cache line per group)
        float4 qr[8];
        #pragma unroll
        for (int c = 0; c < 8; ++c) qr[c] = *(const float4*)&qbase[nn*HD + c*4];

        // phase 1: lane dl fully scores keys t*8+dl -> Ps[qs][j]; no shuffles
        #pragma unroll 2
        for (int t = 0; t < 12; ++t) {
            const int j = t*8 + dl;
            float s0 = 0.f, s1 = 0.f, s2 = 0.f, s3 = 0.f;
            #pragma unroll
            for (int c = 0; c < 8; ++c) {
                float4 w = *(const float4*)&Ks[j*KP + c*4];
                s0 = fmaf(qr[c].x, w.x, s0);
                s1 = fmaf(qr[c].y, w.y, s1);
                s2 = fmaf(qr[c].z, w.z, s2);
                s3 = fmaf(qr[c].w, w.w, s3);
            }
            Ps[qs][j] = ((s0 + s1) + (s2 + s3)) * scale;   // wave-coherent
        }

        // softmax over the 96 scores: re-read own 12 (static offsets)
        float raw[12];
        #pragma unroll
        for (int t = 0; t < 12; ++t) raw[t] = Ps[qs][t*8 + dl];
        float m = -INFINITY;
        #pragma unroll
        for (int t = 0; t < 12; ++t) m = fmaxf(m, raw[t]);
        #pragma unroll
        for (int o = 1; o < 8; o <<= 1) m = fmaxf(m, __shfl_xor(m, o));
        float l = 0.f;
        #pragma unroll
        for (int t = 0; t < 12; ++t) l += __expf(raw[t] - m);
        #pragma unroll
        for (int o = 1; o < 8; o <<= 1) l += __shfl_xor(l, o);
        const float inv = 1.0f / l;
        #pragma unroll
        for (int t = 0; t < 12; ++t) Ps[qs][t*8 + dl] = __expf(raw[t] - m) * inv;

        // phase 2: weighted V sum; p via LDS broadcast (no shuffles)
        float a0 = 0.f, a1 = 0.f, a2 = 0.f, a3 = 0.f;
        #pragma unroll 4
        for (int j = 0; j < TK; ++j) {
            const float p = Ps[qs][j];                       // 8-lane broadcast
            float4 vv = *(const float4*)&Vs[j*HD + dl*4];    // bcast across groups
            a0 = fmaf(p, vv.x, a0);
            a1 = fmaf(p, vv.y, a1);
            a2 = fmaf(p, vv.z, a2);
            a3 = fmaf(p, vv.w, a3);
        }

        if (act) {
            float* op = out + (b*NN + nn)*CC + hh*HD + dl*4;
            *(float4*)op = make_float4(a0, a1, a2, a3);
        }
    }
}

// ---------------------------------------------------------------------------
extern "C" void kernel_launch(void* const* d_in, const int* in_sizes, int n_in,
                              void* d_out, int out_size, void* d_ws, size_t ws_size,
                              hipStream_t stream)
{
    const float* x      = (const float*)d_in[0];   // [B,H,W,C] = [3200, 384]
    const float* w_qkv  = (const float*)d_in[1];   // [1152, 384]
    const float* w_gp   = (const float*)d_in[2];   // [48, 384] -> (12,48,32)
    const float* w_proj = (const float*)d_in[3];   // [384, 384]
    float* out = (float*)d_out;                    // [B,H,W,C]

    float* ws = (float*)d_ws;
    float* q        = ws;                 // [B,h,N,d] 1228800
    float* kk       = ws + 1228800;
    float* vv       = ws + 2457600;
    float* attn_out = ws + 3686400;       // [B,N,h*d] 1228800
    float* scores   = ws + 4915200;       // [1152][1600] 1843200
    float* qmean    = ws + 6758400;       // [1152][32]   36864
    int*   iws      = (int*)(ws + 6795264);
    int*   gidx     = iws;                // 38400
    int*   topk     = iws + 38400;        // 110592
    int*   qperm    = iws + 38400 + 110592;            // 38400
    int*   qoff     = iws + 38400 + 110592 + 38400;    // 1152
    int*   qcnt     = qoff + 1152;                     // 1152

    // 1) QKV projection, scatter into q/k/v
    gemm_tile<0><<<dim3(QKV_COLS/64, (NB*NN)/64), 256, 0, stream>>>(
        x, w_qkv, q, kk, vv, NB*NN, QKV_COLS, CC);

    // 2) query -> group routing
    group_route<<<NQ/256, 256, 0, stream>>>(q, w_gp, gidx);

    // 3a) deterministic group means (branchless) + query buckets
    qmean_all2<<<BHN*GN, 256, 0, stream>>>(q, gidx, qmean, qperm, qoff, qcnt);

    // 3b) group->key score matrix
    score_all<<<dim3(7, BHN), 256, 0, stream>>>(qmean, kk, scores);

    // 3c) per-wave barrier-free radix top-96
    topk_radix<<<(BHN*GN)/4, 256, 0, stream>>>(scores, topk);

    // 4) group-bucketed sparse attention, shuffle-free phase 1 (2304 blocks)
    sparse_attn8<<<BHN*GN*2, 256, 0, stream>>>(q, kk, vv, topk, qperm, qoff, qcnt, attn_out);

    // 5) output projection
    gemm_tile<1><<<dim3(CC/64, (NB*NN)/64), 256, 0, stream>>>(
        attn_out, w_proj, out, nullptr, nullptr, NB*NN, CC, CC);
}

// Round 15
// 242.918 us; speedup vs baseline: 2.4105x; 1.0095x over previous
//
#include <hip/hip_runtime.h>
#include <math.h>

#define NH 12
#define HD 32
#define GN 48
#define TK 96
#define NB 2
#define NN 1600
#define CC 384
#define BHN (NB*NH)          // 24
#define QKV_COLS (3*NH*HD)   // 1152
#define NQ (BHN*NN)          // 38400 total (b,h,n) queries
#define KP 36                // padded K row: bank-quad = 4*((row+chunk)%8)
#define LP 68                // gemm LDS row pad: 68%32=4 -> 2-way writes (free)

// ---------------------------------------------------------------------------
// GEMM: out = A[M,K] @ B[N,K]^T   (both row-major; B rows are output cols)
// MODE 0: scatter epilogue into q/k/v [B,h,N,d]   MODE 1: plain store [M,N]
// Round-15 structure: SINGLE LDS buffer (r14 dbuf cost occupancy 24->16% and
// regressed) + next-tile register prefetch issued BEFORE the compute block
// (load latency hides under the 512-cycle FMA block, not the barrier).
// Barrier count == r13; accumulation order unchanged (bitwise-identical).
// ---------------------------------------------------------------------------
template<int MODE>
__global__ __launch_bounds__(256)
void gemm_tile(const float* __restrict__ A, const float* __restrict__ B,
               float* __restrict__ o0, float* __restrict__ o1, float* __restrict__ o2,
               int M, int N, int K)
{
    __shared__ float As[16][LP];
    __shared__ float Bs[16][LP];
    const int tid = threadIdx.x;
    const int tx = tid & 15, ty = tid >> 4;
    const int m0 = blockIdx.y * 64, n0 = blockIdx.x * 64;
    const int lr = tid >> 2;          // tile row 0..63
    const int lc = (tid & 3) * 4;     // k-seg 0,4,8,12
    const float* __restrict__ Ap = &A[(m0 + lr) * K + lc];
    const float* __restrict__ Bp = &B[(n0 + lr) * K + lc];
    float acc[4][4] = {};

    // prologue: stage tile 0
    {
        float4 av = *(const float4*)Ap;
        float4 bv = *(const float4*)Bp;
        As[lc+0][lr] = av.x; As[lc+1][lr] = av.y; As[lc+2][lr] = av.z; As[lc+3][lr] = av.w;
        Bs[lc+0][lr] = bv.x; Bs[lc+1][lr] = bv.y; Bs[lc+2][lr] = bv.z; Bs[lc+3][lr] = bv.w;
    }
    __syncthreads();

    for (int k0 = 16; k0 <= K; k0 += 16) {
        // 1) issue next-tile loads FIRST — latency hides under compute below
        const bool more = (k0 < K);
        float4 av_n, bv_n;
        if (more) {
            av_n = *(const float4*)(Ap + k0);
            bv_n = *(const float4*)(Bp + k0);
        }
        // 2) compute current tile (~512 VALU cycles/wave)
        #pragma unroll
        for (int kk = 0; kk < 16; ++kk) {
            float4 a4 = *(const float4*)&As[kk][ty*4];
            float4 b4 = *(const float4*)&Bs[kk][tx*4];
            float a[4] = {a4.x, a4.y, a4.z, a4.w};
            float b[4] = {b4.x, b4.y, b4.z, b4.w};
            #pragma unroll
            for (int i = 0; i < 4; ++i)
                #pragma unroll
                for (int j = 0; j < 4; ++j)
                    acc[i][j] = fmaf(a[i], b[j], acc[i][j]);
        }
        // 3) overwrite the (single) buffer with the prefetched tile
        if (more) {
            __syncthreads();   // all waves done reading
            As[lc+0][lr] = av_n.x; As[lc+1][lr] = av_n.y;
            As[lc+2][lr] = av_n.z; As[lc+3][lr] = av_n.w;
            Bs[lc+0][lr] = bv_n.x; Bs[lc+1][lr] = bv_n.y;
            Bs[lc+2][lr] = bv_n.z; Bs[lc+3][lr] = bv_n.w;
            __syncthreads();   // writes visible
        }
    }

    if (MODE == 0) {
        #pragma unroll
        for (int i = 0; i < 4; ++i) {
            int row = m0 + ty*4 + i;
            int b  = row / NN;
            int nn = row - b * NN;
            #pragma unroll
            for (int j = 0; j < 4; ++j) {
                int col = n0 + tx*4 + j;
                int which = col / CC;          // uniform per tile (384 % 64 == 0)
                int rem = col - which * CC;
                int hh = rem >> 5, dd = rem & 31;
                float* dst = (which == 0) ? o0 : (which == 1) ? o1 : o2;
                dst[((b*NH + hh)*NN + nn)*HD + dd] = acc[i][j];
            }
        }
    } else {
        #pragma unroll
        for (int i = 0; i < 4; ++i) {
            int row = m0 + ty*4 + i;
            float4 st = make_float4(acc[i][0], acc[i][1], acc[i][2], acc[i][3]);
            *(float4*)&o0[row * N + n0 + tx*4] = st;
        }
    }
}

// ---------------------------------------------------------------------------
// Kernel 2: per-query group argmax (gidx), strict > == jnp.argmax tie-break
// ---------------------------------------------------------------------------
__global__ __launch_bounds__(256)
void group_route(const float* __restrict__ q, const float* __restrict__ wgp,
                 int* __restrict__ gidx)
{
    int t = blockIdx.x * 256 + threadIdx.x;   // [0, NQ)
    int bh = t / NN;
    int hh = bh % NH;
    const float* qp = q + t * HD;
    float qr[HD];
    #pragma unroll
    for (int i = 0; i < HD; i += 4) {
        float4 x = *(const float4*)&qp[i];
        qr[i] = x.x; qr[i+1] = x.y; qr[i+2] = x.z; qr[i+3] = x.w;
    }
    float best = -INFINITY; int bg = 0;
    for (int g = 0; g < GN; ++g) {
        const float* gp = wgp + hh*GN*HD + g*HD;
        float s = 0.f;
        #pragma unroll
        for (int i = 0; i < HD; i += 4) {
            float4 w = *(const float4*)&gp[i];
            s += qr[i]*w.x + qr[i+1]*w.y + qr[i+2]*w.z + qr[i+3]*w.w;
        }
        if (s > best) { best = s; bg = g; }
    }
    gidx[t] = bg;
}

// ---------------------------------------------------------------------------
// Kernel 3a (v4): per-(bh,g) deterministic group-mean, branchless always-load
// + query bucketing (qperm/qoff/qcnt). 1152 blocks.
// ---------------------------------------------------------------------------
__global__ __launch_bounds__(256)
void qmean_all2(const float* __restrict__ q, const int* __restrict__ gidx,
                float* __restrict__ qmean, int* __restrict__ qperm,
                int* __restrict__ qoff, int* __restrict__ qcnt)
{
    __shared__ float part[8][HD];
    __shared__ int   cnts[8];
    __shared__ int   off_s, pos_s;
    const int bid = blockIdx.x;       // bh*GN + g
    const int g = bid % GN, bh = bid / GN;
    const int tid = threadIdx.x;
    const int s = tid >> 5, dd = tid & 31;

    const int* __restrict__ gx = gidx + bh*NN;
    const float* __restrict__ qb = q + bh*NN*HD;

    if (tid == 0) { off_s = 0; pos_s = 0; }

    const int base = s * 200;         // 1600/8 rows per slice, contiguous
    float p = 0.f; int c = 0;
    #pragma unroll 2
    for (int n0 = 0; n0 < 200; n0 += 4) {
        int4 g4 = *(const int4*)&gx[base + n0];
        float v0 = qb[(base+n0+0)*HD + dd];   // unconditional: pipelines
        float v1 = qb[(base+n0+1)*HD + dd];
        float v2 = qb[(base+n0+2)*HD + dd];
        float v3 = qb[(base+n0+3)*HD + dd];
        if (g4.x == g) { p += v0; c++; }      // cndmask+add, no branch
        if (g4.y == g) { p += v1; c++; }
        if (g4.z == g) { p += v2; c++; }
        if (g4.w == g) { p += v3; c++; }
    }
    part[s][dd] = p;
    if (dd == 0) cnts[s] = c;
    __syncthreads();                  // part[] + off_s/pos_s init visible

    if (tid < HD) {
        float sum = 0.f; int ct = 0;
        #pragma unroll
        for (int ss = 0; ss < 8; ++ss) { sum += part[ss][tid]; ct += cnts[ss]; }
        qmean[bid*HD + tid] = ct ? sum / (float)ct : 0.f;
    }

    // bucketing: offset = #queries in groups < g (gx row is L1-hot now)
    int mo = 0;
    for (int n = tid; n < NN; n += 256) mo += (gx[n] < g);
    atomicAdd(&off_s, mo);
    __syncthreads();
    for (int n = tid; n < NN; n += 256) {
        if (gx[n] == g) {
            int pp = atomicAdd(&pos_s, 1);
            qperm[bh*NN + off_s + pp] = n;
        }
    }
    __syncthreads();
    if (tid == 0) { qoff[bid] = off_s; qcnt[bid] = pos_s; }
}

// ---------------------------------------------------------------------------
// Kernel 3b: scores[bh*GN+g][n] = qmean[bh,g] . k[bh,n]. Thread owns one n,
// k-row in registers, qmean tile in LDS (broadcast reads), coalesced stores.
// ---------------------------------------------------------------------------
__global__ __launch_bounds__(256)
void score_all(const float* __restrict__ qmean, const float* __restrict__ k,
               float* __restrict__ scores)
{
    __shared__ float Qs[GN][HD];          // 6 KB
    const int bh = blockIdx.y;
    const int tid = threadIdx.x;
    const int n = blockIdx.x*256 + tid;
    for (int i = tid; i < GN*HD; i += 256)
        ((float*)Qs)[i] = qmean[bh*GN*HD + i];
    __syncthreads();
    if (n >= NN) return;
    const float* __restrict__ kp = k + (bh*NN + n)*HD;
    float4 kr[8];
    #pragma unroll
    for (int c = 0; c < 8; ++c) kr[c] = *(const float4*)&kp[c*4];
    for (int g = 0; g < GN; ++g) {
        float s = 0.f;
        #pragma unroll
        for (int c = 0; c < 8; ++c) {
            float4 qv = *(const float4*)&Qs[g][c*4];   // same-addr broadcast
            s += kr[c].x*qv.x + kr[c].y*qv.y + kr[c].z*qv.z + kr[c].w*qv.w;
        }
        scores[(bh*GN + g)*NN + n] = s;               // coalesced per g
    }
}

// ---------------------------------------------------------------------------
// Kernel 3c: per-WAVE barrier-free radix top-96. Each 64-lane wave owns one
// (bh,g) row of 1600 scores: keys + 256-bin hist live in per-wave LDS slices
// (DS ops from a wave complete in program order -> no __syncthreads).
// Suffix-scan in registers via shfl; pivot via ballot; collect via ballot-
// compaction in ascending index order (== lax.top_k lowest-index ties).
// ---------------------------------------------------------------------------
__global__ __launch_bounds__(256)
void topk_radix(const float* __restrict__ scores, int* __restrict__ topk)
{
    __shared__ unsigned keysL[4][NN];     // 25.6 KB
    __shared__ unsigned histL[4][256];    // 4 KB
    const int tid = threadIdx.x;
    const int w = tid >> 6, lane = tid & 63;
    const int gid = blockIdx.x*4 + w;     // (bh*GN + g) in [0,1152)
    const float* __restrict__ row = scores + gid*NN;
    unsigned* keys = keysL[w];
    unsigned* hist = histL[w];

    // load + order-preserving transform (1600 = 25*64 exactly)
    #pragma unroll
    for (int i = 0; i < 25; ++i) {
        int m = lane + 64*i;
        unsigned u = __float_as_uint(row[m]);
        u = (u & 0x80000000u) ? ~u : (u | 0x80000000u);
        keys[m] = u;
    }

    unsigned prefix = 0, r = TK;
    #pragma unroll
    for (int pass = 0; pass < 4; ++pass) {
        const int shift = 24 - 8*pass;
        #pragma unroll
        for (int j = 0; j < 4; ++j) hist[lane*4 + j] = 0;
        #pragma unroll
        for (int i = 0; i < 25; ++i) {
            unsigned u = keys[lane + 64*i];
            bool match = (pass == 0) || ((u >> (shift+8)) == (prefix >> (shift+8)));
            if (match) atomicAdd(&hist[(u >> shift) & 255u], 1u);
        }
        // suffix scan: lane holds bins 4L..4L+3
        uint4 h = *(const uint4*)&hist[lane*4];
        unsigned s3 = h.w, s2 = h.z + s3, s1 = h.y + s2, s0 = h.x + s1;
        unsigned I = s0;                      // inclusive suffix over lane totals
        #pragma unroll
        for (int off = 1; off < 64; off <<= 1) {
            unsigned t = __shfl_down(I, off);
            if (lane + off < 64) I += t;
        }
        unsigned E = I - s0;                  // strict suffix (lanes > L)
        unsigned sf[5] = {E+s0, E+s1, E+s2, E+s3, E};
        int bj = -1; unsigned subc = 0;
        #pragma unroll
        for (int j = 0; j < 4; ++j)
            if (sf[j] >= r && sf[j+1] < r) { bj = j; subc = sf[j+1]; }
        unsigned long long mask = __ballot(bj >= 0);   // exactly one bit set
        int src = __ffsll(mask) - 1;
        int bstar = __shfl(lane*4 + bj, src);
        unsigned sub = (unsigned)__shfl((int)subc, src);
        prefix |= ((unsigned)bstar) << shift;
        r -= sub;
    }
    const unsigned P = prefix;   // exact 96th-largest key; r = #equals to take

    // collect: all keys > P, then first r keys == P (ascending index)
    int* tko = topk + gid*TK;
    int base = 0;
    #pragma unroll
    for (int i = 0; i < 25; ++i) {
        int m = lane + 64*i;
        bool gt = (keys[m] > P);
        unsigned long long mask = __ballot(gt);
        if (gt) tko[base + __popcll(mask & ((1ull << lane) - 1ull))] = m;
        base += (int)__popcll(mask);
    }
    #pragma unroll
    for (int i = 0; i < 25; ++i) {
        int m = lane + 64*i;
        bool eq = (keys[m] == P);
        unsigned long long mask = __ballot(eq);
        if (eq) {
            int pos = base + (int)__popcll(mask & ((1ull << lane) - 1ull));
            if (pos < TK) tko[pos] = m;
        }
        base += (int)__popcll(mask);
    }
}

// ---------------------------------------------------------------------------
// Kernel 4 (v8): group-bucketed attention, shuffle-free phase 1 (padded Ks),
// LDS score buffer Ps, split-S. Verified round 12: dropped out of top-5.
// ---------------------------------------------------------------------------
__global__ __launch_bounds__(256)
void sparse_attn8(const float* __restrict__ q, const float* __restrict__ k,
                  const float* __restrict__ v, const int* __restrict__ topk,
                  const int* __restrict__ qperm, const int* __restrict__ qoff,
                  const int* __restrict__ qcnt, float* __restrict__ out)
{
    __shared__ float Ks[TK*KP];      // 13.8 KB (padded rows)
    __shared__ float Vs[TK*HD];      // 12 KB
    __shared__ float Ps[32][104];    // 13.3 KB, padded row (104%32==8)

    const int sub = blockIdx.x & 1;       // split-S half
    const int bid = blockIdx.x >> 1;      // bh*GN + g
    const int bh = bid / GN;
    const int nq = qcnt[bid];
    if (nq <= sub*32) return;             // this half has no work (uniform)
    const int off = qoff[bid];
    const int tid = threadIdx.x;

    const int* __restrict__ tk = topk + bid*TK;
    const float* __restrict__ kb = k + bh*NN*HD;
    const float* __restrict__ vb = v + bh*NN*HD;

    // stage K (padded) and V: 8 consecutive lanes fetch one 128B row
    for (int idx = tid; idx < TK*8; idx += 256) {
        int row = idx >> 3, ch = idx & 7;
        int r = tk[row];
        *(float4*)&Ks[row*KP + ch*4] = *(const float4*)&kb[r*HD + ch*4];
        ((float4*)Vs)[idx] = *(const float4*)&vb[r*HD + ch*4];
    }
    __syncthreads();

    const float scale = 0.17677669529663687f;   // 32^-0.5
    const int qs = tid >> 3;            // query slot 0..31 (Ps row owner)
    const int dl = tid & 7;             // lane in 8-lane group
    const int b = bh / NH, hh = bh - b*NH;
    const float* __restrict__ qbase = q + bh*NN*HD;
    const int* __restrict__ qlist = qperm + bh*NN + off;

    for (int it0 = sub*32; it0 < nq; it0 += 64) {
        const int qi = it0 + qs;
        const bool act = (qi < nq);
        const int nn = qlist[act ? qi : nq-1];   // safe clamp; group-uniform

        // full q row (8-lane same-address reads: one cache line per group)
        float4 qr[8];
        #pragma unroll
        for (int c = 0; c < 8; ++c) qr[c] = *(const float4*)&qbase[nn*HD + c*4];

        // phase 1: lane dl fully scores keys t*8+dl -> Ps[qs][j]; no shuffles
        #pragma unroll 2
        for (int t = 0; t < 12; ++t) {
            const int j = t*8 + dl;
            float s0 = 0.f, s1 = 0.f, s2 = 0.f, s3 = 0.f;
            #pragma unroll
            for (int c = 0; c < 8; ++c) {
                float4 w = *(const float4*)&Ks[j*KP + c*4];
                s0 = fmaf(qr[c].x, w.x, s0);
                s1 = fmaf(qr[c].y, w.y, s1);
                s2 = fmaf(qr[c].z, w.z, s2);
                s3 = fmaf(qr[c].w, w.w, s3);
            }
            Ps[qs][j] = ((s0 + s1) + (s2 + s3)) * scale;   // wave-coherent
        }

        // softmax over the 96 scores: re-read own 12 (static offsets)
        float raw[12];
        #pragma unroll
        for (int t = 0; t < 12; ++t) raw[t] = Ps[qs][t*8 + dl];
        float m = -INFINITY;
        #pragma unroll
        for (int t = 0; t < 12; ++t) m = fmaxf(m, raw[t]);
        #pragma unroll
        for (int o = 1; o < 8; o <<= 1) m = fmaxf(m, __shfl_xor(m, o));
        float l = 0.f;
        #pragma unroll
        for (int t = 0; t < 12; ++t) l += __expf(raw[t] - m);
        #pragma unroll
        for (int o = 1; o < 8; o <<= 1) l += __shfl_xor(l, o);
        const float inv = 1.0f / l;
        #pragma unroll
        for (int t = 0; t < 12; ++t) Ps[qs][t*8 + dl] = __expf(raw[t] - m) * inv;

        // phase 2: weighted V sum; p via LDS broadcast (no shuffles)
        float a0 = 0.f, a1 = 0.f, a2 = 0.f, a3 = 0.f;
        #pragma unroll 4
        for (int j = 0; j < TK; ++j) {
            const float p = Ps[qs][j];                       // 8-lane broadcast
            float4 vv = *(const float4*)&Vs[j*HD + dl*4];    // bcast across groups
            a0 = fmaf(p, vv.x, a0);
            a1 = fmaf(p, vv.y, a1);
            a2 = fmaf(p, vv.z, a2);
            a3 = fmaf(p, vv.w, a3);
        }

        if (act) {
            float* op = out + (b*NN + nn)*CC + hh*HD + dl*4;
            *(float4*)op = make_float4(a0, a1, a2, a3);
        }
    }
}

// ---------------------------------------------------------------------------
extern "C" void kernel_launch(void* const* d_in, const int* in_sizes, int n_in,
                              void* d_out, int out_size, void* d_ws, size_t ws_size,
                              hipStream_t stream)
{
    const float* x      = (const float*)d_in[0];   // [B,H,W,C] = [3200, 384]
    const float* w_qkv  = (const float*)d_in[1];   // [1152, 384]
    const float* w_gp   = (const float*)d_in[2];   // [48, 384] -> (12,48,32)
    const float* w_proj = (const float*)d_in[3];   // [384, 384]
    float* out = (float*)d_out;                    // [B,H,W,C]

    float* ws = (float*)d_ws;
    float* q        = ws;                 // [B,h,N,d] 1228800
    float* kk       = ws + 1228800;
    float* vv       = ws + 2457600;
    float* attn_out = ws + 3686400;       // [B,N,h*d] 1228800
    float* scores   = ws + 4915200;       // [1152][1600] 1843200
    float* qmean    = ws + 6758400;       // [1152][32]   36864
    int*   iws      = (int*)(ws + 6795264);
    int*   gidx     = iws;                // 38400
    int*   topk     = iws + 38400;        // 110592
    int*   qperm    = iws + 38400 + 110592;            // 38400
    int*   qoff     = iws + 38400 + 110592 + 38400;    // 1152
    int*   qcnt     = qoff + 1152;                     // 1152

    // 1) QKV projection, scatter into q/k/v
    gemm_tile<0><<<dim3(QKV_COLS/64, (NB*NN)/64), 256, 0, stream>>>(
        x, w_qkv, q, kk, vv, NB*NN, QKV_COLS, CC);

    // 2) query -> group routing
    group_route<<<NQ/256, 256, 0, stream>>>(q, w_gp, gidx);

    // 3a) deterministic group means (branchless) + query buckets
    qmean_all2<<<BHN*GN, 256, 0, stream>>>(q, gidx, qmean, qperm, qoff, qcnt);

    // 3b) group->key score matrix
    score_all<<<dim3(7, BHN), 256, 0, stream>>>(qmean, kk, scores);

    // 3c) per-wave barrier-free radix top-96
    topk_radix<<<(BHN*GN)/4, 256, 0, stream>>>(scores, topk);

    // 4) group-bucketed sparse attention, shuffle-free phase 1 (2304 blocks)
    sparse_attn8<<<BHN*GN*2, 256, 0, stream>>>(q, kk, vv, topk, qperm, qoff, qcnt, attn_out);

    // 5) output projection
    gemm_tile<1><<<dim3(CC/64, (NB*NN)/64), 256, 0, stream>>>(
        attn_out, w_proj, out, nullptr, nullptr, NB*NN, CC, CC);
}